// Round 1
// 624.854 us; speedup vs baseline: 1.0471x; 1.0471x over previous
//
#include <hip/hip_runtime.h>

#define B_   4
#define NB_  262144
#define NA_  8192
#define NB_SHIFT 18

typedef short bf16x8 __attribute__((ext_vector_type(8)));
typedef float f32x4  __attribute__((ext_vector_type(4)));

// ---------------- helpers ----------------
__device__ __forceinline__ float bflo(unsigned int u){ return __uint_as_float(u << 16); }
__device__ __forceinline__ float bfhi(unsigned int u){ return __uint_as_float(u & 0xffff0000u); }
__device__ __forceinline__ unsigned short f2bf(float f){
  unsigned int u = __float_as_uint(f);
  u += 0x7fffu + ((u >> 16) & 1u);   // round-to-nearest-even
  return (unsigned short)(u >> 16);
}
// HW packed f32->bf16 (RNE, same as f2bf) — 1 instr instead of ~9
__device__ __forceinline__ unsigned int packbf(float a, float b){
  unsigned int r;
  asm("v_cvt_pk_bf16_f32 %0, %1, %2" : "=v"(r) : "v"(a), "v"(b));
  return r;
}
__device__ __forceinline__ float softplus_f(float v){
  return fmaxf(v, 0.0f) + __logf(1.0f + __expf(-fabsf(v)));
}
__device__ __forceinline__ void store32f(float* dst, const float* v){
  float4* p = reinterpret_cast<float4*>(dst);
  #pragma unroll
  for (int q = 0; q < 8; ++q)
    p[q] = make_float4(v[4*q+0], v[4*q+1], v[4*q+2], v[4*q+3]);
}

// stage 32 f32 from src into 16 packed-bf16-pair LDS rows r0..r0+15 (row stride = ncol)
__device__ __forceinline__ void stage32(unsigned int* xbuf, int tid, int r0,
                                        const float* __restrict__ src, int ncol){
  const float4* p = reinterpret_cast<const float4*>(src);
  #pragma unroll
  for (int q = 0; q < 8; ++q){
    float4 v = p[q];
    xbuf[(r0 + 2*q    )*ncol + tid] = packbf(v.x, v.y);
    xbuf[(r0 + 2*q + 1)*ncol + tid] = packbf(v.z, v.w);
  }
}

// layers 2 (64->64) + 3 (64->32) VALU path; h1 in 32 packed rows. Columns thread-private.
__device__ __forceinline__ void mlp_tail_packed(unsigned int* hbuf, int tid, int ncol,
                                         const float* __restrict__ W2, const float* __restrict__ B2,
                                         const float* __restrict__ W3, const float* __restrict__ B3,
                                         float* out)
{
  float acc[64];
  #pragma unroll
  for (int j = 0; j < 64; ++j) acc[j] = B2[j];
  for (int k2 = 0; k2 < 32; ++k2){
    unsigned int px = hbuf[k2*ncol + tid];
    float x0 = bflo(px), x1 = bfhi(px);
    const float* w = W2 + k2*128;
    #pragma unroll
    for (int j = 0; j < 64; ++j) acc[j] = fmaf(x0, w[j], acc[j]);
    #pragma unroll
    for (int j = 0; j < 64; ++j) acc[j] = fmaf(x1, w[64+j], acc[j]);
  }
  #pragma unroll
  for (int j2 = 0; j2 < 32; ++j2)
    hbuf[j2*ncol + tid] = packbf(softplus_f(acc[2*j2]), softplus_f(acc[2*j2+1]));

  float a3[32];
  #pragma unroll
  for (int j = 0; j < 32; ++j) a3[j] = B3[j];
  for (int k2 = 0; k2 < 32; ++k2){
    unsigned int px = hbuf[k2*ncol + tid];
    float x0 = bflo(px), x1 = bfhi(px);
    const float* w = W3 + k2*64;
    #pragma unroll
    for (int j = 0; j < 32; ++j) a3[j] = fmaf(x0, w[j], a3[j]);
    #pragma unroll
    for (int j = 0; j < 32; ++j) a3[j] = fmaf(x1, w[32+j], a3[j]);
  }
  #pragma unroll
  for (int j = 0; j < 32; ++j) out[j] = softplus_f(a3[j]);
}

// ---------------- weight prep: concat the 18 f32 arrays ----------------
struct WPtrs { const float* p[18]; };

__global__ __launch_bounds__(256) void prep_kernel(WPtrs wp, float* __restrict__ W){
  int i = blockIdx.x * 256 + threadIdx.x;
  if (i >= 39392) return;
  int idx = i;
  const int sizes[18] = {8192,64,4096,64,2048,32,
                         6144,64,4096,64,2048,32,
                         6144,64,4096,64,2048,32};
  #pragma unroll
  for (int s = 0; s < 18; ++s){
    if (idx < sizes[s]){ W[i] = wp.p[s][idx]; return; }
    idx -= sizes[s];
  }
}

// ---------------- swizzle e-MLP weights into MFMA B-fragment order (bf16) ----------------
__global__ __launch_bounds__(256) void swizzle_kernel(
    const float* __restrict__ ew1, const float* __restrict__ ew2,
    const float* __restrict__ ew3, unsigned short* __restrict__ Wb){
  int i = blockIdx.x*256 + threadIdx.x;
  if (i >= 14336) return;
  int j = i & 7, lane = (i >> 3) & 63;
  int quad = lane >> 4, l16 = lane & 15;
  float v;
  if (i < 8192){
    int g = i >> 9;  int nt = g & 3, kt = g >> 2;
    v = ew1[(kt*32 + quad*8 + j)*64 + nt*16 + l16];
  } else if (i < 12288){
    int g = (i - 8192) >> 9;  int nt = g & 3, kt = g >> 2;
    v = ew2[(kt*32 + quad*8 + j)*64 + nt*16 + l16];
  } else {
    int g = (i - 12288) >> 9;  int nt = g & 1, kt = g >> 1;
    v = ew3[(kt*32 + quad*8 + j)*32 + nt*16 + l16];
  }
  Wb[i] = f2bf(v);
}

// ---------------- CSR build: LDS-histogram counting sort (no contended global atomics) ----
// 64 blocks (16 per batch), 16384 bonds per block. partials/bases laid out [blk][atom].
__global__ __launch_bounds__(256) void hist_lds_kernel(const int* __restrict__ ba1,
                                                       int* __restrict__ partials){
  __shared__ int lh[NA_];
  const int tid = threadIdx.x;
  const int blk = blockIdx.x;
  const int b = blk >> 4;
  const size_t base = (size_t)b*NB_ + (size_t)(blk & 15)*16384;
  #pragma unroll
  for (int i = tid; i < NA_; i += 256) lh[i] = 0;
  __syncthreads();
  for (int it = 0; it < 64; ++it)
    atomicAdd(&lh[ba1[base + it*256 + tid]], 1);
  __syncthreads();
  #pragma unroll
  for (int i = tid; i < NA_; i += 256) partials[blk*NA_ + i] = lh[i];
}

__global__ __launch_bounds__(256) void reduce_kernel(const int* __restrict__ partials,
                                                     int* __restrict__ counts){
  int t = blockIdx.x*256 + threadIdx.x;     // [0, 32768)
  int b = t >> 13, aa = t & (NA_-1);
  int s = 0;
  #pragma unroll
  for (int lb = 0; lb < 16; ++lb) s += partials[(b*16 + lb)*NA_ + aa];
  counts[t] = s;
}

__global__ __launch_bounds__(1024) void scan_kernel(const int* __restrict__ counts,
                                                    int* __restrict__ offsets){
  __shared__ int s[1024];
  const int tid = threadIdx.x;
  const int base = tid * 32;
  int local[32]; int sum = 0;
  #pragma unroll
  for (int i = 0; i < 32; ++i){ local[i] = counts[base + i]; sum += local[i]; }
  s[tid] = sum;
  __syncthreads();
  for (int off = 1; off < 1024; off <<= 1){
    int v = (tid >= off) ? s[tid - off] : 0;
    __syncthreads();
    s[tid] += v;
    __syncthreads();
  }
  int run = s[tid] - sum;
  #pragma unroll
  for (int i = 0; i < 32; ++i){
    offsets[base + i] = run; run += local[i];
  }
}

__global__ __launch_bounds__(256) void base_kernel(const int* __restrict__ offsets,
                                                   const int* __restrict__ partials,
                                                   int* __restrict__ bases){
  int t = blockIdx.x*256 + threadIdx.x;     // [0, 32768)
  int b = t >> 13, aa = t & (NA_-1);
  int run = offsets[t];
  #pragma unroll
  for (int lb = 0; lb < 16; ++lb){
    int g = (b*16 + lb)*NA_ + aa;
    bases[g] = run; run += partials[g];
  }
}

__global__ __launch_bounds__(256) void fill_lds_kernel(const int* __restrict__ ba1,
                                                       const int* __restrict__ bases,
                                                       int* __restrict__ list){
  __shared__ int lh[NA_];
  const int tid = threadIdx.x;
  const int blk = blockIdx.x;
  const int b = blk >> 4;
  const size_t base = (size_t)b*NB_ + (size_t)(blk & 15)*16384;
  #pragma unroll
  for (int i = tid; i < NA_; i += 256) lh[i] = 0;
  __syncthreads();
  for (int it = 0; it < 64; ++it){
    int idx = it*256 + tid;
    int a = ba1[base + idx];
    int rank = atomicAdd(&lh[a], 1);
    list[bases[blk*NA_ + a] + rank] = (int)((base + idx) & (NB_ - 1));
  }
}

// ---------------- stage 1: bonds MLP via MFMA (128->64->64->32) ----------------
__global__ __launch_bounds__(256) void bonds_kernel(
    const float* __restrict__ bonds,
    const int* __restrict__ ba1,
    const int* __restrict__ ba2,
    const float* __restrict__ atoms,
    const float* __restrict__ state,
    const float* __restrict__ W,            // f32 concat (biases)
    const unsigned short* __restrict__ Wb,  // swizzled bf16 e-weights
    float* __restrict__ bonds_out)
{
  __shared__ unsigned short hred[4][64*72];
  const int tid  = threadIdx.x;
  const int wave = tid >> 6, lane = tid & 63;
  const int quad = lane >> 4, l16 = lane & 15;
  const int b = blockIdx.y;
  const int rowbase = blockIdx.x*256 + wave*64;   // bond row within batch
  unsigned short* H = &hred[wave][0];

  int r[4], g1[4], g2[4];
  #pragma unroll
  for (int t = 0; t < 4; ++t){
    r[t]  = rowbase + t*16 + l16;
    g1[t] = ba1[(size_t)b*NB_ + r[t]];
    g2[t] = ba2[(size_t)b*NB_ + r[t]];
  }

  // ----- layer 1: [64x128] @ [128x64] -----
  f32x4 acc[4][4] = {};
  #pragma unroll
  for (int kt = 0; kt < 4; ++kt){
    bf16x8 bf[4];
    #pragma unroll
    for (int nt = 0; nt < 4; ++nt)
      bf[nt] = *(const bf16x8*)(Wb + ((kt*4 + nt)*64 + lane)*8);
    #pragma unroll
    for (int t = 0; t < 4; ++t){
      const float* src;
      if      (kt == 0) src = atoms + ((size_t)b*NA_ + g1[t])*32 + quad*8;
      else if (kt == 1) src = atoms + ((size_t)b*NA_ + g2[t])*32 + quad*8;
      else if (kt == 2) src = bonds + ((size_t)b*NB_ + r[t])*32 + quad*8;
      else              src = state + (size_t)b*32 + quad*8;
      float4 v0 = *(const float4*)(src);
      float4 v1 = *(const float4*)(src + 4);
      union { bf16x8 v; unsigned int u[4]; } af;
      af.u[0] = packbf(v0.x, v0.y);
      af.u[1] = packbf(v0.z, v0.w);
      af.u[2] = packbf(v1.x, v1.y);
      af.u[3] = packbf(v1.z, v1.w);
      #pragma unroll
      for (int nt = 0; nt < 4; ++nt)
        acc[t][nt] = __builtin_amdgcn_mfma_f32_16x16x32_bf16(af.v, bf[nt], acc[t][nt], 0, 0, 0);
    }
  }
  // bias + softplus -> H1 (bf16, [64 m][64 n], stride 72)
  {
    const float* b1v = W + 8192;
    #pragma unroll
    for (int nt = 0; nt < 4; ++nt){
      float bias = b1v[nt*16 + l16];
      #pragma unroll
      for (int t = 0; t < 4; ++t){
        #pragma unroll
        for (int rg = 0; rg < 4; ++rg){
          int m = t*16 + quad*4 + rg;
          H[m*72 + nt*16 + l16] = f2bf(softplus_f(acc[t][nt][rg] + bias));
        }
      }
    }
  }

  // ----- layer 2: [64x64] @ [64x64] -----
  f32x4 acc2[4][4] = {};
  #pragma unroll
  for (int kt = 0; kt < 2; ++kt){
    bf16x8 bf[4];
    #pragma unroll
    for (int nt = 0; nt < 4; ++nt)
      bf[nt] = *(const bf16x8*)(Wb + 8192 + ((kt*4 + nt)*64 + lane)*8);
    #pragma unroll
    for (int t = 0; t < 4; ++t){
      bf16x8 af = *(const bf16x8*)(H + (t*16 + l16)*72 + kt*32 + quad*8);
      #pragma unroll
      for (int nt = 0; nt < 4; ++nt)
        acc2[t][nt] = __builtin_amdgcn_mfma_f32_16x16x32_bf16(af, bf[nt], acc2[t][nt], 0, 0, 0);
    }
  }
  {
    const float* b2v = W + 12352;
    #pragma unroll
    for (int nt = 0; nt < 4; ++nt){
      float bias = b2v[nt*16 + l16];
      #pragma unroll
      for (int t = 0; t < 4; ++t){
        #pragma unroll
        for (int rg = 0; rg < 4; ++rg){
          int m = t*16 + quad*4 + rg;
          H[m*72 + nt*16 + l16] = f2bf(softplus_f(acc2[t][nt][rg] + bias));
        }
      }
    }
  }

  // ----- layer 3: [64x64] @ [64x32] -----
  f32x4 acc3[4][2] = {};
  #pragma unroll
  for (int kt = 0; kt < 2; ++kt){
    bf16x8 bf[2];
    #pragma unroll
    for (int nt = 0; nt < 2; ++nt)
      bf[nt] = *(const bf16x8*)(Wb + 12288 + ((kt*2 + nt)*64 + lane)*8);
    #pragma unroll
    for (int t = 0; t < 4; ++t){
      bf16x8 af = *(const bf16x8*)(H + (t*16 + l16)*72 + kt*32 + quad*8);
      #pragma unroll
      for (int nt = 0; nt < 2; ++nt)
        acc3[t][nt] = __builtin_amdgcn_mfma_f32_16x16x32_bf16(af, bf[nt], acc3[t][nt], 0, 0, 0);
    }
  }
  {
    const float* b3v = W + 14464;
    #pragma unroll
    for (int nt = 0; nt < 2; ++nt){
      float bias = b3v[nt*16 + l16];
      #pragma unroll
      for (int t = 0; t < 4; ++t){
        #pragma unroll
        for (int rg = 0; rg < 4; ++rg){
          int m = t*16 + quad*4 + rg;
          bonds_out[((size_t)b*NB_ + rowbase + m)*32 + nt*16 + l16] =
              softplus_f(acc3[t][nt][rg] + bias);
        }
      }
    }
  }
}

// ---------------- gather: sum bonds_out rows per atom -> packed bf16 bta ----------------
__global__ __launch_bounds__(256) void gather_kernel(
    const int* __restrict__ counts,
    const int* __restrict__ offsets,
    const int* __restrict__ list,
    const float* __restrict__ bonds_out,
    unsigned int* __restrict__ btap)
{
  int i = blockIdx.x*256 + threadIdx.x;   // [0, B*NA*8)
  int p = i & 7;
  int row = i >> 3;                        // b*NA + atom
  int b = row >> 13;                       // NA = 2^13
  int c = counts[row], o = offsets[row];
  const float* basep = bonds_out + (size_t)b*NB_*32 + p*4;
  float4 acc = make_float4(0.f, 0.f, 0.f, 0.f);
  int t = 0;
  for (; t + 2 <= c; t += 2){
    int i0 = list[o+t], i1 = list[o+t+1];
    float4 v0 = *(const float4*)(basep + (size_t)i0*32);
    float4 v1 = *(const float4*)(basep + (size_t)i1*32);
    acc.x += v0.x + v1.x; acc.y += v0.y + v1.y;
    acc.z += v0.z + v1.z; acc.w += v0.w + v1.w;
  }
  if (t < c){
    int i0 = list[o+t];
    float4 v0 = *(const float4*)(basep + (size_t)i0*32);
    acc.x += v0.x; acc.y += v0.y; acc.z += v0.z; acc.w += v0.w;
  }
  btap[(size_t)row*16 + p*2    ] = packbf(acc.x, acc.y);
  btap[(size_t)row*16 + p*2 + 1] = packbf(acc.z, acc.w);
}

// ---------------- stage 2: atoms MLP (96->64->64->32) ----------------
__global__ __launch_bounds__(64) void atoms_kernel(
    const float* __restrict__ atoms,
    const float* __restrict__ state,
    const float* __restrict__ W,
    const int* __restrict__ counts,
    const unsigned int* __restrict__ btap,
    float* __restrict__ atoms_out,
    float* __restrict__ bondsum,
    float* __restrict__ atomsum)
{
  __shared__ unsigned int xbuf[48*64];
  const int tid = threadIdx.x;            // one wave
  const int b = blockIdx.y;
  const int row = b*NA_ + blockIdx.x*64 + tid;

  float braw[32];
  {
    const uint4* pb = reinterpret_cast<const uint4*>(btap + (size_t)row*16);
    #pragma unroll
    for (int q = 0; q < 4; ++q){
      uint4 v = pb[q];
      braw[8*q+0]=bflo(v.x); braw[8*q+1]=bfhi(v.x);
      braw[8*q+2]=bflo(v.y); braw[8*q+3]=bfhi(v.y);
      braw[8*q+4]=bflo(v.z); braw[8*q+5]=bfhi(v.z);
      braw[8*q+6]=bflo(v.w); braw[8*q+7]=bfhi(v.w);
    }
  }
  const float inv = 1.0f / (float)counts[row];
  #pragma unroll
  for (int q = 0; q < 16; ++q)
    xbuf[q*64 + tid] = packbf(braw[2*q]*inv, braw[2*q+1]*inv);     // v_in 0..31
  stage32(xbuf, tid, 16, atoms + (size_t)row*32, 64);              // v_in 32..63
  stage32(xbuf, tid, 32, state + (size_t)b*32,   64);              // v_in 64..95

  float acc[64];
  {
    const float* Bl = W + 6144;
    #pragma unroll
    for (int j = 0; j < 64; ++j) acc[j] = Bl[j];
  }
  for (int k2 = 0; k2 < 48; ++k2){
    unsigned int px = xbuf[k2*64 + tid];
    float x0 = bflo(px), x1 = bfhi(px);
    const float* w = W + k2*128;
    #pragma unroll
    for (int j = 0; j < 64; ++j) acc[j] = fmaf(x0, w[j], acc[j]);
    #pragma unroll
    for (int j = 0; j < 64; ++j) acc[j] = fmaf(x1, w[64+j], acc[j]);
  }
  #pragma unroll
  for (int j2 = 0; j2 < 32; ++j2)
    xbuf[j2*64 + tid] = packbf(softplus_f(acc[2*j2]), softplus_f(acc[2*j2+1]));

  float out[32];
  mlp_tail_packed(xbuf, tid, 64, W + 6208, W + 10304, W + 10368, W + 12416, out);
  store32f(atoms_out + (size_t)row*32, out);

  #pragma unroll
  for (int f = 0; f < 32; ++f){
    float v = braw[f];
    #pragma unroll
    for (int s = 1; s < 64; s <<= 1) v += __shfl_xor(v, s);
    if (tid == 0) unsafeAtomicAdd(&bondsum[b*32 + f], v);
  }
  #pragma unroll
  for (int f = 0; f < 32; ++f){
    float v = out[f];
    #pragma unroll
    for (int s = 1; s < 64; s <<= 1) v += __shfl_xor(v, s);
    if (tid == 0) unsafeAtomicAdd(&atomsum[b*32 + f], v);
  }
}

// ---------------- stage 3: state MLP (96->64->64->32), 4 rows ----------------
__global__ __launch_bounds__(256) void state_kernel(
    const float* __restrict__ state,
    const float* __restrict__ W,
    const float* __restrict__ bondsum,
    const float* __restrict__ atomsum,
    float* __restrict__ state_out)
{
  __shared__ float uin[4][96];
  __shared__ float h1s[4][64];
  __shared__ float h2s[4][64];
  const int tid = threadIdx.x;
  const int b = tid >> 6;
  const int j = tid & 63;
  if (j < 32){
    uin[b][j]      = bondsum[b*32 + j] * (1.0f/(float)NB_);
    uin[b][32 + j] = atomsum[b*32 + j] * (1.0f/(float)NA_);
    uin[b][64 + j] = state[(size_t)b*32 + j];
  }
  __syncthreads();
  float a1 = W[6144 + j];
  for (int k = 0; k < 96; ++k) a1 = fmaf(uin[b][k], W[k*64 + j], a1);
  h1s[b][j] = softplus_f(a1);
  __syncthreads();
  float a2 = W[10304 + j];
  for (int k = 0; k < 64; ++k) a2 = fmaf(h1s[b][k], W[6208 + k*64 + j], a2);
  h2s[b][j] = softplus_f(a2);
  __syncthreads();
  if (j < 32){
    float a3 = W[12416 + j];
    for (int k = 0; k < 64; ++k) a3 = fmaf(h2s[b][k], W[10368 + k*32 + j], a3);
    state_out[b*32 + j] = softplus_f(a3);
  }
}

// ---------------- launcher ----------------
// ws (4-byte units): counts[32768]@0 | offsets@32768 | (unused)@65536 | list[1048576]@98304 |
//   btap[524288]@1146880 | bondsum[128]@1671168 | atomsum[128]@1671296 |
//   W f32[39392]@1671424 | Wb u16[14336]@1710816 — total ~6.87 MB
// Aliases: partials[64*8192]@list (dead before fill writes list);
//          bases[64*8192]@btap (dead before gather writes btap).
extern "C" void kernel_launch(void* const* d_in, const int* in_sizes, int n_in,
                              void* d_out, int out_size, void* d_ws, size_t ws_size,
                              hipStream_t stream)
{
  (void)in_sizes; (void)n_in; (void)out_size; (void)ws_size;
  const float* bonds = (const float*)d_in[0];
  const int*   ba1   = (const int*)d_in[1];
  const int*   ba2   = (const int*)d_in[2];
  const float* atoms = (const float*)d_in[3];
  const float* state = (const float*)d_in[4];

  int*          counts  = (int*)d_ws;
  int*          offsets = counts + 32768;
  int*          list    = counts + 98304;
  unsigned int* btap    = (unsigned int*)d_ws + 1146880;
  float*        bondsum = (float*)d_ws + 1671168;
  float*        atomsum = (float*)d_ws + 1671296;
  float*        W       = (float*)d_ws + 1671424;
  unsigned short* Wb    = (unsigned short*)((unsigned int*)d_ws + 1710816);

  int* partials = list;           // 524288 ints, dead before fill overwrites list
  int* bases    = (int*)btap;     // 524288 ints, dead before gather overwrites btap

  hipMemsetAsync(bondsum, 0, 256 * sizeof(float), stream);

  WPtrs wp;
  for (int s = 0; s < 18; ++s) wp.p[s] = (const float*)d_in[5 + s];
  prep_kernel<<<154, 256, 0, stream>>>(wp, W);
  swizzle_kernel<<<56, 256, 0, stream>>>((const float*)d_in[5], (const float*)d_in[7],
                                         (const float*)d_in[9], Wb);

  // CSR build — counting sort with LDS histograms, no contended global atomics
  hist_lds_kernel<<<64, 256, 0, stream>>>(ba1, partials);
  reduce_kernel<<<128, 256, 0, stream>>>(partials, counts);
  scan_kernel<<<1, 1024, 0, stream>>>(counts, offsets);
  base_kernel<<<128, 256, 0, stream>>>(offsets, partials, bases);
  fill_lds_kernel<<<64, 256, 0, stream>>>(ba1, bases, list);

  float* out_bonds = (float*)d_out;
  float* out_atoms = out_bonds + (size_t)B_*NB_*32;
  float* out_state = out_atoms + (size_t)B_*NA_*32;

  bonds_kernel<<<dim3(NB_/256, B_), 256, 0, stream>>>(bonds, ba1, ba2, atoms, state,
                                                      W, Wb, out_bonds);
  gather_kernel<<<(B_*NA_*8)/256, 256, 0, stream>>>(counts, offsets, list, out_bonds, btap);
  atoms_kernel<<<dim3(NA_/64, B_), 64, 0, stream>>>(atoms, state, W + 14496,
                                                    counts, btap, out_atoms, bondsum, atomsum);
  state_kernel<<<1, 256, 0, stream>>>(state, W + 26944, bondsum, atomsum, out_state);
}

// Round 2
// 613.335 us; speedup vs baseline: 1.0668x; 1.0188x over previous
//
#include <hip/hip_runtime.h>

#define B_   4
#define NB_  262144
#define NA_  8192
#define NB_SHIFT 18

typedef short bf16x8 __attribute__((ext_vector_type(8)));
typedef float f32x4  __attribute__((ext_vector_type(4)));

// ---------------- helpers ----------------
__device__ __forceinline__ float bflo(unsigned int u){ return __uint_as_float(u << 16); }
__device__ __forceinline__ float bfhi(unsigned int u){ return __uint_as_float(u & 0xffff0000u); }
__device__ __forceinline__ unsigned short f2bf(float f){
  unsigned int u = __float_as_uint(f);
  u += 0x7fffu + ((u >> 16) & 1u);   // round-to-nearest-even
  return (unsigned short)(u >> 16);
}
// HW packed f32->bf16 (RNE, same as f2bf) — 1 instr
__device__ __forceinline__ unsigned int packbf(float a, float b){
  unsigned int r;
  asm("v_cvt_pk_bf16_f32 %0, %1, %2" : "=v"(r) : "v"(a), "v"(b));
  return r;
}
__device__ __forceinline__ float softplus_f(float v){
  return fmaxf(v, 0.0f) + __logf(1.0f + __expf(-fabsf(v)));
}
__device__ __forceinline__ void store32f(float* dst, const float* v){
  float4* p = reinterpret_cast<float4*>(dst);
  #pragma unroll
  for (int q = 0; q < 8; ++q)
    p[q] = make_float4(v[4*q+0], v[4*q+1], v[4*q+2], v[4*q+3]);
}

// stage 32 f32 from src into 16 packed-bf16-pair LDS rows r0..r0+15 (row stride = ncol)
__device__ __forceinline__ void stage32(unsigned int* xbuf, int tid, int r0,
                                        const float* __restrict__ src, int ncol){
  const float4* p = reinterpret_cast<const float4*>(src);
  #pragma unroll
  for (int q = 0; q < 8; ++q){
    float4 v = p[q];
    xbuf[(r0 + 2*q    )*ncol + tid] = packbf(v.x, v.y);
    xbuf[(r0 + 2*q + 1)*ncol + tid] = packbf(v.z, v.w);
  }
}

// layers 2 (64->64) + 3 (64->32) VALU path; h1 in 32 packed rows. Columns thread-private.
__device__ __forceinline__ void mlp_tail_packed(unsigned int* hbuf, int tid, int ncol,
                                         const float* __restrict__ W2, const float* __restrict__ B2,
                                         const float* __restrict__ W3, const float* __restrict__ B3,
                                         float* out)
{
  float acc[64];
  #pragma unroll
  for (int j = 0; j < 64; ++j) acc[j] = B2[j];
  for (int k2 = 0; k2 < 32; ++k2){
    unsigned int px = hbuf[k2*ncol + tid];
    float x0 = bflo(px), x1 = bfhi(px);
    const float* w = W2 + k2*128;
    #pragma unroll
    for (int j = 0; j < 64; ++j) acc[j] = fmaf(x0, w[j], acc[j]);
    #pragma unroll
    for (int j = 0; j < 64; ++j) acc[j] = fmaf(x1, w[64+j], acc[j]);
  }
  #pragma unroll
  for (int j2 = 0; j2 < 32; ++j2)
    hbuf[j2*ncol + tid] = packbf(softplus_f(acc[2*j2]), softplus_f(acc[2*j2+1]));

  float a3[32];
  #pragma unroll
  for (int j = 0; j < 32; ++j) a3[j] = B3[j];
  for (int k2 = 0; k2 < 32; ++k2){
    unsigned int px = hbuf[k2*ncol + tid];
    float x0 = bflo(px), x1 = bfhi(px);
    const float* w = W3 + k2*64;
    #pragma unroll
    for (int j = 0; j < 32; ++j) a3[j] = fmaf(x0, w[j], a3[j]);
    #pragma unroll
    for (int j = 0; j < 32; ++j) a3[j] = fmaf(x1, w[32+j], a3[j]);
  }
  #pragma unroll
  for (int j = 0; j < 32; ++j) out[j] = softplus_f(a3[j]);
}

// ---------------- weight prep: concat the 18 f32 arrays ----------------
struct WPtrs { const float* p[18]; };

__global__ __launch_bounds__(256) void prep_kernel(WPtrs wp, float* __restrict__ W){
  int i = blockIdx.x * 256 + threadIdx.x;
  if (i >= 39392) return;
  int idx = i;
  const int sizes[18] = {8192,64,4096,64,2048,32,
                         6144,64,4096,64,2048,32,
                         6144,64,4096,64,2048,32};
  #pragma unroll
  for (int s = 0; s < 18; ++s){
    if (idx < sizes[s]){ W[i] = wp.p[s][idx]; return; }
    idx -= sizes[s];
  }
}

// ---------------- effective layer-1 biases: fold the (per-batch constant) state term ----
// be[b][64] = b1e + W1e[96..127]^T state[b] ; bv[b][64] = b1v + W1v[64..95]^T state[b]
__global__ __launch_bounds__(512) void biaseff_kernel(const float* __restrict__ state,
                                                      const float* __restrict__ W,
                                                      float* __restrict__ be,
                                                      float* __restrict__ bv){
  int t = threadIdx.x;
  int b = (t >> 6) & 3, j = t & 63;
  const float* st = state + b*32;
  if (t < 256){
    float a = W[8192 + j];
    #pragma unroll
    for (int k = 0; k < 32; ++k) a = fmaf(st[k], W[(96+k)*64 + j], a);
    be[b*64 + j] = a;
  } else {
    float a = W[14496 + 6144 + j];
    #pragma unroll
    for (int k = 0; k < 32; ++k) a = fmaf(st[k], W[14496 + (64+k)*64 + j], a);
    bv[b*64 + j] = a;
  }
}

// ---------------- swizzle e-MLP weights into MFMA fragment order (bf16) ----------------
// Used as the A operand (W^T as A-frag == W as B-frag, element-for-element):
// lane holds frag[k = quad*8 + j][n = lane&15]
__global__ __launch_bounds__(256) void swizzle_kernel(
    const float* __restrict__ ew1, const float* __restrict__ ew2,
    const float* __restrict__ ew3, unsigned short* __restrict__ Wb){
  int i = blockIdx.x*256 + threadIdx.x;
  if (i >= 14336) return;
  int j = i & 7, lane = (i >> 3) & 63;
  int quad = lane >> 4, l16 = lane & 15;
  float v;
  if (i < 8192){
    int g = i >> 9;  int nt = g & 3, kt = g >> 2;
    v = ew1[(kt*32 + quad*8 + j)*64 + nt*16 + l16];
  } else if (i < 12288){
    int g = (i - 8192) >> 9;  int nt = g & 3, kt = g >> 2;
    v = ew2[(kt*32 + quad*8 + j)*64 + nt*16 + l16];
  } else {
    int g = (i - 12288) >> 9;  int nt = g & 1, kt = g >> 1;
    v = ew3[(kt*32 + quad*8 + j)*32 + nt*16 + l16];
  }
  Wb[i] = f2bf(v);
}

// ---------------- CSR build: LDS-histogram counting sort ----------------
__global__ __launch_bounds__(256) void hist_lds_kernel(const int* __restrict__ ba1,
                                                       int* __restrict__ partials){
  __shared__ int lh[NA_];
  const int tid = threadIdx.x;
  const int blk = blockIdx.x;
  const int b = blk >> 4;
  const size_t base = (size_t)b*NB_ + (size_t)(blk & 15)*16384;
  #pragma unroll
  for (int i = tid; i < NA_; i += 256) lh[i] = 0;
  __syncthreads();
  for (int it = 0; it < 64; ++it)
    atomicAdd(&lh[ba1[base + it*256 + tid]], 1);
  __syncthreads();
  #pragma unroll
  for (int i = tid; i < NA_; i += 256) partials[blk*NA_ + i] = lh[i];
}

__global__ __launch_bounds__(256) void reduce_kernel(const int* __restrict__ partials,
                                                     int* __restrict__ counts){
  int t = blockIdx.x*256 + threadIdx.x;     // [0, 32768)
  int b = t >> 13, aa = t & (NA_-1);
  int s = 0;
  #pragma unroll
  for (int lb = 0; lb < 16; ++lb) s += partials[(b*16 + lb)*NA_ + aa];
  counts[t] = s;
}

__global__ __launch_bounds__(1024) void scan_kernel(const int* __restrict__ counts,
                                                    int* __restrict__ offsets){
  __shared__ int s[1024];
  const int tid = threadIdx.x;
  const int base = tid * 32;
  int local[32]; int sum = 0;
  #pragma unroll
  for (int i = 0; i < 32; ++i){ local[i] = counts[base + i]; sum += local[i]; }
  s[tid] = sum;
  __syncthreads();
  for (int off = 1; off < 1024; off <<= 1){
    int v = (tid >= off) ? s[tid - off] : 0;
    __syncthreads();
    s[tid] += v;
    __syncthreads();
  }
  int run = s[tid] - sum;
  #pragma unroll
  for (int i = 0; i < 32; ++i){
    offsets[base + i] = run; run += local[i];
  }
}

__global__ __launch_bounds__(256) void base_kernel(const int* __restrict__ offsets,
                                                   const int* __restrict__ partials,
                                                   int* __restrict__ bases){
  int t = blockIdx.x*256 + threadIdx.x;     // [0, 32768)
  int b = t >> 13, aa = t & (NA_-1);
  int run = offsets[t];
  #pragma unroll
  for (int lb = 0; lb < 16; ++lb){
    int g = (b*16 + lb)*NA_ + aa;
    bases[g] = run; run += partials[g];
  }
}

__global__ __launch_bounds__(256) void fill_lds_kernel(const int* __restrict__ ba1,
                                                       const int* __restrict__ bases,
                                                       int* __restrict__ list){
  __shared__ int lh[NA_];
  const int tid = threadIdx.x;
  const int blk = blockIdx.x;
  const int b = blk >> 4;
  const size_t base = (size_t)b*NB_ + (size_t)(blk & 15)*16384;
  #pragma unroll
  for (int i = tid; i < NA_; i += 256) lh[i] = 0;
  __syncthreads();
  for (int it = 0; it < 64; ++it){
    int idx = it*256 + tid;
    int a = ba1[base + idx];
    int rank = atomicAdd(&lh[a], 1);
    list[bases[blk*NA_ + a] + rank] = (int)((base + idx) & (NB_ - 1));
  }
}

// ---------------- stage 1: bonds MLP via MFMA, operand-swapped ----------------
// D = W^T (A operand) x X^T (B operand): C/D lane layout col=bond(l16), rows=4
// consecutive FEATURES (quad*4+rg) -> epilogue packs 4 feats into one ds_write_b64,
// layer-3 stores float4. State term pre-folded into bias (be).
__global__ __launch_bounds__(256) void bonds_kernel(
    const float* __restrict__ bonds,
    const int* __restrict__ ba1,
    const int* __restrict__ ba2,
    const float* __restrict__ atoms,
    const float* __restrict__ W,            // f32 concat (biases 2,3)
    const unsigned short* __restrict__ Wb,  // swizzled bf16 e-weights
    const float* __restrict__ be,           // effective bias1 [B][64]
    float* __restrict__ bonds_out)
{
  __shared__ unsigned short hred[4][64*72];
  const int tid  = threadIdx.x;
  const int wave = tid >> 6, lane = tid & 63;
  const int quad = lane >> 4, l16 = lane & 15;
  const int b = blockIdx.y;
  const int rowbase = blockIdx.x*256 + wave*64;   // bond row within batch
  unsigned short* H = &hred[wave][0];

  int r[4], g1[4], g2[4];
  #pragma unroll
  for (int nt = 0; nt < 4; ++nt){
    r[nt]  = rowbase + nt*16 + l16;
    g1[nt] = ba1[(size_t)b*NB_ + r[nt]];
    g2[nt] = ba2[(size_t)b*NB_ + r[nt]];
  }

  // ----- layer 1: [64 feat][96 k] x [96 k][64 bond] (state folded into bias) -----
  f32x4 acc[4][4] = {};    // [mt = feat tile][nt = bond tile]
  #pragma unroll
  for (int kt = 0; kt < 3; ++kt){
    bf16x8 wf[4];
    #pragma unroll
    for (int mt = 0; mt < 4; ++mt)
      wf[mt] = *(const bf16x8*)(Wb + ((kt*4 + mt)*64 + lane)*8);
    #pragma unroll
    for (int nt = 0; nt < 4; ++nt){
      const float* src;
      if      (kt == 0) src = atoms + ((size_t)b*NA_ + g1[nt])*32 + quad*8;
      else if (kt == 1) src = atoms + ((size_t)b*NA_ + g2[nt])*32 + quad*8;
      else              src = bonds + ((size_t)b*NB_ + r[nt])*32 + quad*8;
      float4 v0 = *(const float4*)(src);
      float4 v1 = *(const float4*)(src + 4);
      union { bf16x8 v; unsigned int u[4]; } xf;
      xf.u[0] = packbf(v0.x, v0.y);
      xf.u[1] = packbf(v0.z, v0.w);
      xf.u[2] = packbf(v1.x, v1.y);
      xf.u[3] = packbf(v1.z, v1.w);
      #pragma unroll
      for (int mt = 0; mt < 4; ++mt)
        acc[mt][nt] = __builtin_amdgcn_mfma_f32_16x16x32_bf16(wf[mt], xf.v, acc[mt][nt], 0, 0, 0);
    }
  }
  // bias + softplus -> H1 [bond][feat] stride 72, one b64 write per tile
  {
    const float* b1v = be + b*64;
    #pragma unroll
    for (int mt = 0; mt < 4; ++mt){
      float4 bias = *(const float4*)(b1v + mt*16 + quad*4);
      #pragma unroll
      for (int nt = 0; nt < 4; ++nt){
        unsigned int lo = packbf(softplus_f(acc[mt][nt][0] + bias.x),
                                 softplus_f(acc[mt][nt][1] + bias.y));
        unsigned int hi = packbf(softplus_f(acc[mt][nt][2] + bias.z),
                                 softplus_f(acc[mt][nt][3] + bias.w));
        *reinterpret_cast<uint2*>(H + (nt*16 + l16)*72 + mt*16 + quad*4) = make_uint2(lo, hi);
      }
    }
  }

  // ----- layer 2: [64][64] -----
  f32x4 acc2[4][4] = {};
  #pragma unroll
  for (int kt = 0; kt < 2; ++kt){
    bf16x8 wf[4];
    #pragma unroll
    for (int mt = 0; mt < 4; ++mt)
      wf[mt] = *(const bf16x8*)(Wb + 8192 + ((kt*4 + mt)*64 + lane)*8);
    #pragma unroll
    for (int nt = 0; nt < 4; ++nt){
      bf16x8 hf = *(const bf16x8*)(H + (nt*16 + l16)*72 + kt*32 + quad*8);
      #pragma unroll
      for (int mt = 0; mt < 4; ++mt)
        acc2[mt][nt] = __builtin_amdgcn_mfma_f32_16x16x32_bf16(wf[mt], hf, acc2[mt][nt], 0, 0, 0);
    }
  }
  {
    const float* b2v = W + 12352;
    #pragma unroll
    for (int mt = 0; mt < 4; ++mt){
      float4 bias = *(const float4*)(b2v + mt*16 + quad*4);
      #pragma unroll
      for (int nt = 0; nt < 4; ++nt){
        unsigned int lo = packbf(softplus_f(acc2[mt][nt][0] + bias.x),
                                 softplus_f(acc2[mt][nt][1] + bias.y));
        unsigned int hi = packbf(softplus_f(acc2[mt][nt][2] + bias.z),
                                 softplus_f(acc2[mt][nt][3] + bias.w));
        *reinterpret_cast<uint2*>(H + (nt*16 + l16)*72 + mt*16 + quad*4) = make_uint2(lo, hi);
      }
    }
  }

  // ----- layer 3: [32][64] -----
  f32x4 acc3[2][4] = {};
  #pragma unroll
  for (int kt = 0; kt < 2; ++kt){
    bf16x8 wf[2];
    #pragma unroll
    for (int mt = 0; mt < 2; ++mt)
      wf[mt] = *(const bf16x8*)(Wb + 12288 + ((kt*2 + mt)*64 + lane)*8);
    #pragma unroll
    for (int nt = 0; nt < 4; ++nt){
      bf16x8 hf = *(const bf16x8*)(H + (nt*16 + l16)*72 + kt*32 + quad*8);
      #pragma unroll
      for (int mt = 0; mt < 2; ++mt)
        acc3[mt][nt] = __builtin_amdgcn_mfma_f32_16x16x32_bf16(wf[mt], hf, acc3[mt][nt], 0, 0, 0);
    }
  }
  {
    const float* b3v = W + 14464;
    #pragma unroll
    for (int mt = 0; mt < 2; ++mt){
      float4 bias = *(const float4*)(b3v + mt*16 + quad*4);
      #pragma unroll
      for (int nt = 0; nt < 4; ++nt){
        float4 o;
        o.x = softplus_f(acc3[mt][nt][0] + bias.x);
        o.y = softplus_f(acc3[mt][nt][1] + bias.y);
        o.z = softplus_f(acc3[mt][nt][2] + bias.z);
        o.w = softplus_f(acc3[mt][nt][3] + bias.w);
        *reinterpret_cast<float4*>(bonds_out +
            ((size_t)b*NB_ + rowbase + nt*16 + l16)*32 + mt*16 + quad*4) = o;
      }
    }
  }
}

// ---------------- gather: sum bonds_out rows per atom -> packed bf16 bta ----------------
__global__ __launch_bounds__(256) void gather_kernel(
    const int* __restrict__ counts,
    const int* __restrict__ offsets,
    const int* __restrict__ list,
    const float* __restrict__ bonds_out,
    unsigned int* __restrict__ btap)
{
  int i = blockIdx.x*256 + threadIdx.x;   // [0, B*NA*8)
  int p = i & 7;
  int row = i >> 3;                        // b*NA + atom
  int b = row >> 13;                       // NA = 2^13
  int c = counts[row], o = offsets[row];
  const float* basep = bonds_out + (size_t)b*NB_*32 + p*4;
  float4 acc = make_float4(0.f, 0.f, 0.f, 0.f);
  int t = 0;
  for (; t + 2 <= c; t += 2){
    int i0 = list[o+t], i1 = list[o+t+1];
    float4 v0 = *(const float4*)(basep + (size_t)i0*32);
    float4 v1 = *(const float4*)(basep + (size_t)i1*32);
    acc.x += v0.x + v1.x; acc.y += v0.y + v1.y;
    acc.z += v0.z + v1.z; acc.w += v0.w + v1.w;
  }
  if (t < c){
    int i0 = list[o+t];
    float4 v0 = *(const float4*)(basep + (size_t)i0*32);
    acc.x += v0.x; acc.y += v0.y; acc.z += v0.z; acc.w += v0.w;
  }
  btap[(size_t)row*16 + p*2    ] = packbf(acc.x, acc.y);
  btap[(size_t)row*16 + p*2 + 1] = packbf(acc.z, acc.w);
}

// ---------------- stage 2: atoms MLP (96->64->64->32); state folded into bias ----------
// W(v): w1[96][64] @0 | b1 @6144 | w2 @6208 | b2 @10304 | w3 @10368 | b3 @12416
__global__ __launch_bounds__(64) void atoms_kernel(
    const float* __restrict__ atoms,
    const float* __restrict__ W,
    const int* __restrict__ counts,
    const unsigned int* __restrict__ btap,
    const float* __restrict__ bv,           // effective bias1 [B][64]
    float* __restrict__ atoms_out,
    float* __restrict__ bondsum,
    float* __restrict__ atomsum)
{
  __shared__ unsigned int xbuf[32*64];
  const int tid = threadIdx.x;            // one wave
  const int b = blockIdx.y;
  const int row = b*NA_ + blockIdx.x*64 + tid;

  float braw[32];
  {
    const uint4* pb = reinterpret_cast<const uint4*>(btap + (size_t)row*16);
    #pragma unroll
    for (int q = 0; q < 4; ++q){
      uint4 v = pb[q];
      braw[8*q+0]=bflo(v.x); braw[8*q+1]=bfhi(v.x);
      braw[8*q+2]=bflo(v.y); braw[8*q+3]=bfhi(v.y);
      braw[8*q+4]=bflo(v.z); braw[8*q+5]=bfhi(v.z);
      braw[8*q+6]=bflo(v.w); braw[8*q+7]=bfhi(v.w);
    }
  }
  const float inv = 1.0f / (float)counts[row];
  #pragma unroll
  for (int q = 0; q < 16; ++q)
    xbuf[q*64 + tid] = packbf(braw[2*q]*inv, braw[2*q+1]*inv);     // v_in 0..31
  stage32(xbuf, tid, 16, atoms + (size_t)row*32, 64);              // v_in 32..63

  float acc[64];
  {
    const float* Bl = bv + b*64;
    #pragma unroll
    for (int j = 0; j < 64; ++j) acc[j] = Bl[j];
  }
  for (int k2 = 0; k2 < 32; ++k2){
    unsigned int px = xbuf[k2*64 + tid];
    float x0 = bflo(px), x1 = bfhi(px);
    const float* w = W + k2*128;
    #pragma unroll
    for (int j = 0; j < 64; ++j) acc[j] = fmaf(x0, w[j], acc[j]);
    #pragma unroll
    for (int j = 0; j < 64; ++j) acc[j] = fmaf(x1, w[64+j], acc[j]);
  }
  #pragma unroll
  for (int j2 = 0; j2 < 32; ++j2)
    xbuf[j2*64 + tid] = packbf(softplus_f(acc[2*j2]), softplus_f(acc[2*j2+1]));

  float out[32];
  mlp_tail_packed(xbuf, tid, 64, W + 6208, W + 10304, W + 10368, W + 12416, out);
  store32f(atoms_out + (size_t)row*32, out);

  #pragma unroll
  for (int f = 0; f < 32; ++f){
    float v = braw[f];
    #pragma unroll
    for (int s = 1; s < 64; s <<= 1) v += __shfl_xor(v, s);
    if (tid == 0) unsafeAtomicAdd(&bondsum[b*32 + f], v);
  }
  #pragma unroll
  for (int f = 0; f < 32; ++f){
    float v = out[f];
    #pragma unroll
    for (int s = 1; s < 64; s <<= 1) v += __shfl_xor(v, s);
    if (tid == 0) unsafeAtomicAdd(&atomsum[b*32 + f], v);
  }
}

// ---------------- stage 3: state MLP (96->64->64->32), 4 rows ----------------
__global__ __launch_bounds__(256) void state_kernel(
    const float* __restrict__ state,
    const float* __restrict__ W,
    const float* __restrict__ bondsum,
    const float* __restrict__ atomsum,
    float* __restrict__ state_out)
{
  __shared__ float uin[4][96];
  __shared__ float h1s[4][64];
  __shared__ float h2s[4][64];
  const int tid = threadIdx.x;
  const int b = tid >> 6;
  const int j = tid & 63;
  if (j < 32){
    uin[b][j]      = bondsum[b*32 + j] * (1.0f/(float)NB_);
    uin[b][32 + j] = atomsum[b*32 + j] * (1.0f/(float)NA_);
    uin[b][64 + j] = state[(size_t)b*32 + j];
  }
  __syncthreads();
  float a1 = W[6144 + j];
  for (int k = 0; k < 96; ++k) a1 = fmaf(uin[b][k], W[k*64 + j], a1);
  h1s[b][j] = softplus_f(a1);
  __syncthreads();
  float a2 = W[10304 + j];
  for (int k = 0; k < 64; ++k) a2 = fmaf(h1s[b][k], W[6208 + k*64 + j], a2);
  h2s[b][j] = softplus_f(a2);
  __syncthreads();
  if (j < 32){
    float a3 = W[12416 + j];
    for (int k = 0; k < 64; ++k) a3 = fmaf(h2s[b][k], W[10368 + k*32 + j], a3);
    state_out[b*32 + j] = softplus_f(a3);
  }
}

// ---------------- launcher ----------------
// ws (4-byte units): counts[32768]@0 | offsets@32768 | (unused)@65536 | list[1048576]@98304 |
//   btap[524288]@1146880 | bondsum[128]@1671168 | atomsum[128]@1671296 |
//   W f32[39392]@1671424 | Wb u16[14336]@1710816 (7168 dw) | be[256]@1717984 | bv[256]@1718240
// Aliases: partials@list (dead before fill writes list); bases@btap (dead before gather).
extern "C" void kernel_launch(void* const* d_in, const int* in_sizes, int n_in,
                              void* d_out, int out_size, void* d_ws, size_t ws_size,
                              hipStream_t stream)
{
  (void)in_sizes; (void)n_in; (void)out_size; (void)ws_size;
  const float* bonds = (const float*)d_in[0];
  const int*   ba1   = (const int*)d_in[1];
  const int*   ba2   = (const int*)d_in[2];
  const float* atoms = (const float*)d_in[3];
  const float* state = (const float*)d_in[4];

  int*          counts  = (int*)d_ws;
  int*          offsets = counts + 32768;
  int*          list    = counts + 98304;
  unsigned int* btap    = (unsigned int*)d_ws + 1146880;
  float*        bondsum = (float*)d_ws + 1671168;
  float*        atomsum = (float*)d_ws + 1671296;
  float*        W       = (float*)d_ws + 1671424;
  unsigned short* Wb    = (unsigned short*)((unsigned int*)d_ws + 1710816);
  float*        be      = (float*)d_ws + 1717984;
  float*        bv      = (float*)d_ws + 1718240;

  int* partials = list;           // dead before fill overwrites list
  int* bases    = (int*)btap;     // dead before gather overwrites btap

  hipMemsetAsync(bondsum, 0, 256 * sizeof(float), stream);

  WPtrs wp;
  for (int s = 0; s < 18; ++s) wp.p[s] = (const float*)d_in[5 + s];
  prep_kernel<<<154, 256, 0, stream>>>(wp, W);
  biaseff_kernel<<<1, 512, 0, stream>>>(state, W, be, bv);
  swizzle_kernel<<<56, 256, 0, stream>>>((const float*)d_in[5], (const float*)d_in[7],
                                         (const float*)d_in[9], Wb);

  // CSR build — counting sort with LDS histograms
  hist_lds_kernel<<<64, 256, 0, stream>>>(ba1, partials);
  reduce_kernel<<<128, 256, 0, stream>>>(partials, counts);
  scan_kernel<<<1, 1024, 0, stream>>>(counts, offsets);
  base_kernel<<<128, 256, 0, stream>>>(offsets, partials, bases);
  fill_lds_kernel<<<64, 256, 0, stream>>>(ba1, bases, list);

  float* out_bonds = (float*)d_out;
  float* out_atoms = out_bonds + (size_t)B_*NB_*32;
  float* out_state = out_atoms + (size_t)B_*NA_*32;

  bonds_kernel<<<dim3(NB_/256, B_), 256, 0, stream>>>(bonds, ba1, ba2, atoms,
                                                      W, Wb, be, out_bonds);
  gather_kernel<<<(B_*NA_*8)/256, 256, 0, stream>>>(counts, offsets, list, out_bonds, btap);
  atoms_kernel<<<dim3(NA_/64, B_), 64, 0, stream>>>(atoms, W + 14496,
                                                    counts, btap, bv, out_atoms,
                                                    bondsum, atomsum);
  state_kernel<<<1, 256, 0, stream>>>(state, W + 26944, bondsum, atomsum, out_state);
}

// Round 4
// 542.691 us; speedup vs baseline: 1.2057x; 1.1302x over previous
//
#include <hip/hip_runtime.h>

#define B_   4
#define NB_  262144
#define NA_  8192
#define NB_SHIFT 18

typedef short bf16x8 __attribute__((ext_vector_type(8)));
typedef float f32x4  __attribute__((ext_vector_type(4)));

// ---------------- helpers ----------------
__device__ __forceinline__ float bflo(unsigned int u){ return __uint_as_float(u << 16); }
__device__ __forceinline__ float bfhi(unsigned int u){ return __uint_as_float(u & 0xffff0000u); }
__device__ __forceinline__ unsigned short f2bf(float f){
  unsigned int u = __float_as_uint(f);
  u += 0x7fffu + ((u >> 16) & 1u);   // round-to-nearest-even
  return (unsigned short)(u >> 16);
}
// HW packed f32->bf16 (RNE, same as f2bf) — 1 instr
__device__ __forceinline__ unsigned int packbf(float a, float b){
  unsigned int r;
  asm("v_cvt_pk_bf16_f32 %0, %1, %2" : "=v"(r) : "v"(a), "v"(b));
  return r;
}
__device__ __forceinline__ float softplus_f(float v){
  return fmaxf(v, 0.0f) + __logf(1.0f + __expf(-fabsf(v)));
}
// zero-cost compiler fence: orders LDS writes vs reads for intra-wave cross-lane
// communication (per-thread offsets are disjoint, so without this the compiler may
// reorder ds_write/ds_read; HW DS pipe is in-order per wave once program order is fixed)
__device__ __forceinline__ void lds_fence(){
  asm volatile("" ::: "memory");
  __builtin_amdgcn_wave_barrier();
  __builtin_amdgcn_sched_barrier(0);
}

// ---------------- weight prep: concat the 18 f32 arrays ----------------
struct WPtrs { const float* p[18]; };

__global__ __launch_bounds__(256) void prep_kernel(WPtrs wp, float* __restrict__ W){
  int i = blockIdx.x * 256 + threadIdx.x;
  if (i >= 39392) return;
  int idx = i;
  const int sizes[18] = {8192,64,4096,64,2048,32,
                         6144,64,4096,64,2048,32,
                         6144,64,4096,64,2048,32};
  #pragma unroll
  for (int s = 0; s < 18; ++s){
    if (idx < sizes[s]){ W[i] = wp.p[s][idx]; return; }
    idx -= sizes[s];
  }
}

// ---------------- effective layer-1 biases: fold the (per-batch constant) state term ----
__global__ __launch_bounds__(512) void biaseff_kernel(const float* __restrict__ state,
                                                      const float* __restrict__ W,
                                                      float* __restrict__ be,
                                                      float* __restrict__ bv){
  int t = threadIdx.x;
  int b = (t >> 6) & 3, j = t & 63;
  const float* st = state + b*32;
  if (t < 256){
    float a = W[8192 + j];
    #pragma unroll
    for (int k = 0; k < 32; ++k) a = fmaf(st[k], W[(96+k)*64 + j], a);
    be[b*64 + j] = a;
  } else {
    float a = W[14496 + 6144 + j];
    #pragma unroll
    for (int k = 0; k < 32; ++k) a = fmaf(st[k], W[14496 + (64+k)*64 + j], a);
    bv[b*64 + j] = a;
  }
}

// ---------------- swizzle e- and v-MLP weights into MFMA A-fragment order (bf16) -------
// lane holds frag[k = quad*8 + j][col = lane&15]  (W^T-as-A == W-as-B element-for-element)
__global__ __launch_bounds__(256) void swizzle_kernel(
    const float* __restrict__ ew1, const float* __restrict__ ew2,
    const float* __restrict__ ew3,
    const float* __restrict__ vw1, const float* __restrict__ vw2,
    const float* __restrict__ vw3,
    unsigned short* __restrict__ Wb, unsigned short* __restrict__ Wbv){
  int i = blockIdx.x*256 + threadIdx.x;
  if (i >= 24576) return;
  int j = i & 7, lane = (i >> 3) & 63;
  int quad = lane >> 4, l16 = lane & 15;
  int krow = quad*8 + j;
  float v;
  if (i < 14336){
    if (i < 8192){
      int g = i >> 9;  int mt = g & 3, kt = g >> 2;
      v = ew1[(kt*32 + krow)*64 + mt*16 + l16];
    } else if (i < 12288){
      int g = (i - 8192) >> 9;  int mt = g & 3, kt = g >> 2;
      v = ew2[(kt*32 + krow)*64 + mt*16 + l16];
    } else {
      int g = (i - 12288) >> 9;  int mt = g & 1, kt = g >> 1;
      v = ew3[(kt*32 + krow)*32 + mt*16 + l16];
    }
    Wb[i] = f2bf(v);
  } else {
    int o = i - 14336;
    if (o < 4096){
      int g = o >> 9;  int mt = g & 3, kt = g >> 2;     // kt<2: rows 0..63 (state folded)
      v = vw1[(kt*32 + krow)*64 + mt*16 + l16];
    } else if (o < 8192){
      int g = (o - 4096) >> 9;  int mt = g & 3, kt = g >> 2;
      v = vw2[(kt*32 + krow)*64 + mt*16 + l16];
    } else {
      int g = (o - 8192) >> 9;  int mt = g & 1, kt = g >> 1;
      v = vw3[(kt*32 + krow)*32 + mt*16 + l16];
    }
    Wbv[o] = f2bf(v);
  }
}

// ---------------- CSR build: LDS-histogram counting sort ----------------
__global__ __launch_bounds__(1024) void hist_lds_kernel(const int* __restrict__ ba1,
                                                        int* __restrict__ partials){
  __shared__ int lh[NA_];
  const int tid = threadIdx.x;
  const int blk = blockIdx.x;
  const int b = blk >> 4;
  const size_t base = (size_t)b*NB_ + (size_t)(blk & 15)*16384;
  #pragma unroll
  for (int i = tid; i < NA_; i += 1024) lh[i] = 0;
  __syncthreads();
  #pragma unroll
  for (int it = 0; it < 16; ++it)
    atomicAdd(&lh[ba1[base + it*1024 + tid]], 1);
  __syncthreads();
  #pragma unroll
  for (int i = tid; i < NA_; i += 1024) partials[blk*NA_ + i] = lh[i];
}

__global__ __launch_bounds__(256) void reduce_kernel(const int* __restrict__ partials,
                                                     int* __restrict__ counts){
  int t = blockIdx.x*256 + threadIdx.x;     // [0, 32768)
  int b = t >> 13, aa = t & (NA_-1);
  int s = 0;
  #pragma unroll
  for (int lb = 0; lb < 16; ++lb) s += partials[(b*16 + lb)*NA_ + aa];
  counts[t] = s;
}

__global__ __launch_bounds__(1024) void scan_kernel(const int* __restrict__ counts,
                                                    int* __restrict__ offsets){
  __shared__ int s[1024];
  const int tid = threadIdx.x;
  const int base = tid * 32;
  int local[32]; int sum = 0;
  #pragma unroll
  for (int i = 0; i < 32; ++i){ local[i] = counts[base + i]; sum += local[i]; }
  s[tid] = sum;
  __syncthreads();
  for (int off = 1; off < 1024; off <<= 1){
    int v = (tid >= off) ? s[tid - off] : 0;
    __syncthreads();
    s[tid] += v;
    __syncthreads();
  }
  int run = s[tid] - sum;
  #pragma unroll
  for (int i = 0; i < 32; ++i){
    offsets[base + i] = run; run += local[i];
  }
}

__global__ __launch_bounds__(256) void base_kernel(const int* __restrict__ offsets,
                                                   const int* __restrict__ partials,
                                                   int* __restrict__ bases){
  int t = blockIdx.x*256 + threadIdx.x;     // [0, 32768)
  int b = t >> 13, aa = t & (NA_-1);
  int run = offsets[t];
  #pragma unroll
  for (int lb = 0; lb < 16; ++lb){
    int g = (b*16 + lb)*NA_ + aa;
    bases[g] = run; run += partials[g];
  }
}

__global__ __launch_bounds__(1024) void fill_lds_kernel(const int* __restrict__ ba1,
                                                        const int* __restrict__ bases,
                                                        int* __restrict__ list){
  __shared__ int lh[NA_];
  const int tid = threadIdx.x;
  const int blk = blockIdx.x;
  const int b = blk >> 4;
  const size_t base = (size_t)b*NB_ + (size_t)(blk & 15)*16384;
  #pragma unroll
  for (int i = tid; i < NA_; i += 1024) lh[i] = 0;
  __syncthreads();
  #pragma unroll
  for (int it = 0; it < 16; ++it){
    int idx = it*1024 + tid;
    int a = ba1[base + idx];
    int rank = atomicAdd(&lh[a], 1);
    list[bases[blk*NA_ + a] + rank] = (int)((base + idx) & (NB_ - 1));
  }
}

// ---------------- stage 1: bonds MLP via MFMA, nt-sequential, tiny LDS ----------------
// Per wave: 64 bonds, processed as four independent 16-bond chains. LDS 16x72 shorts/wave.
__global__ __launch_bounds__(256, 5) void bonds_kernel(
    const float* __restrict__ bonds,
    const int* __restrict__ ba1,
    const int* __restrict__ ba2,
    const float* __restrict__ atoms,
    const float* __restrict__ W,            // f32 concat (biases 2,3)
    const unsigned short* __restrict__ Wb,  // swizzled bf16 e-weights
    const float* __restrict__ be,           // effective bias1 [B][64]
    float* __restrict__ bonds_out)
{
  __shared__ unsigned short hsall[4][1160];   // 16*72 used, +8 pad
  const int tid  = threadIdx.x;
  const int wave = tid >> 6, lane = tid & 63;
  const int quad = lane >> 4, l16 = lane & 15;
  const int b = blockIdx.y;
  const int rowbase = blockIdx.x*256 + wave*64;
  unsigned short* hwr = &hsall[wave][0] + l16*72;   // this lane's LDS row

  int r[4], g1[4], g2[4];
  #pragma unroll
  for (int nt = 0; nt < 4; ++nt){
    r[nt]  = rowbase + nt*16 + l16;
    g1[nt] = ba1[(size_t)b*NB_ + r[nt]];
    g2[nt] = ba2[(size_t)b*NB_ + r[nt]];
  }

  #pragma unroll
  for (int nt = 0; nt < 4; ++nt){
    // ----- layer 1: [64 feat][96 k] x [96 k][16 bond] -----
    f32x4 a1[4] = {};
    #pragma unroll
    for (int kt = 0; kt < 3; ++kt){
      const float* src;
      if      (kt == 0) src = atoms + ((size_t)b*NA_ + g1[nt])*32 + quad*8;
      else if (kt == 1) src = atoms + ((size_t)b*NA_ + g2[nt])*32 + quad*8;
      else              src = bonds + ((size_t)b*NB_ + r[nt])*32 + quad*8;
      float4 v0 = *(const float4*)(src);
      float4 v1 = *(const float4*)(src + 4);
      union { bf16x8 v; unsigned int u[4]; } xf;
      xf.u[0] = packbf(v0.x, v0.y);
      xf.u[1] = packbf(v0.z, v0.w);
      xf.u[2] = packbf(v1.x, v1.y);
      xf.u[3] = packbf(v1.z, v1.w);
      #pragma unroll
      for (int mt = 0; mt < 4; ++mt){
        bf16x8 wf = *(const bf16x8*)(Wb + ((kt*4 + mt)*64 + lane)*8);
        a1[mt] = __builtin_amdgcn_mfma_f32_16x16x32_bf16(wf, xf.v, a1[mt], 0, 0, 0);
      }
    }
    lds_fence();   // order vs previous nt's layer-3 LDS reads
    #pragma unroll
    for (int mt = 0; mt < 4; ++mt){
      float4 bias = *(const float4*)(be + b*64 + mt*16 + quad*4);
      unsigned int lo = packbf(softplus_f(a1[mt][0] + bias.x), softplus_f(a1[mt][1] + bias.y));
      unsigned int hi = packbf(softplus_f(a1[mt][2] + bias.z), softplus_f(a1[mt][3] + bias.w));
      *reinterpret_cast<uint2*>(hwr + mt*16 + quad*4) = make_uint2(lo, hi);
    }
    lds_fence();   // H1 writes before cross-lane H1 reads

    // ----- layer 2: [64][64] -----
    f32x4 a2[4] = {};
    #pragma unroll
    for (int kt = 0; kt < 2; ++kt){
      bf16x8 hf = *(const bf16x8*)(hwr + kt*32 + quad*8);
      #pragma unroll
      for (int mt = 0; mt < 4; ++mt){
        bf16x8 wf = *(const bf16x8*)(Wb + 8192 + ((kt*4 + mt)*64 + lane)*8);
        a2[mt] = __builtin_amdgcn_mfma_f32_16x16x32_bf16(wf, hf, a2[mt], 0, 0, 0);
      }
    }
    lds_fence();   // H1 reads before H2 overwrites
    #pragma unroll
    for (int mt = 0; mt < 4; ++mt){
      float4 bias = *(const float4*)(W + 12352 + mt*16 + quad*4);
      unsigned int lo = packbf(softplus_f(a2[mt][0] + bias.x), softplus_f(a2[mt][1] + bias.y));
      unsigned int hi = packbf(softplus_f(a2[mt][2] + bias.z), softplus_f(a2[mt][3] + bias.w));
      *reinterpret_cast<uint2*>(hwr + mt*16 + quad*4) = make_uint2(lo, hi);
    }
    lds_fence();   // H2 writes before cross-lane H2 reads

    // ----- layer 3: [32][64] -----
    f32x4 a3[2] = {};
    #pragma unroll
    for (int kt = 0; kt < 2; ++kt){
      bf16x8 hf = *(const bf16x8*)(hwr + kt*32 + quad*8);
      #pragma unroll
      for (int mt = 0; mt < 2; ++mt){
        bf16x8 wf = *(const bf16x8*)(Wb + 12288 + ((kt*2 + mt)*64 + lane)*8);
        a3[mt] = __builtin_amdgcn_mfma_f32_16x16x32_bf16(wf, hf, a3[mt], 0, 0, 0);
      }
    }
    #pragma unroll
    for (int mt = 0; mt < 2; ++mt){
      float4 bias = *(const float4*)(W + 14464 + mt*16 + quad*4);
      float4 o;
      o.x = softplus_f(a3[mt][0] + bias.x);
      o.y = softplus_f(a3[mt][1] + bias.y);
      o.z = softplus_f(a3[mt][2] + bias.z);
      o.w = softplus_f(a3[mt][3] + bias.w);
      *reinterpret_cast<float4*>(bonds_out + ((size_t)b*NB_ + r[nt])*32 + mt*16 + quad*4) = o;
    }
  }
}

// ---------------- gather: mean of bonds_out rows per atom -> packed bf16 (pre-divided) --
__global__ __launch_bounds__(256) void gather_kernel(
    const int* __restrict__ counts,
    const int* __restrict__ offsets,
    const int* __restrict__ list,
    const float* __restrict__ bonds_out,
    unsigned int* __restrict__ btap)
{
  int i = blockIdx.x*256 + threadIdx.x;   // [0, B*NA*8)
  int p = i & 7;
  int row = i >> 3;                        // b*NA + atom
  int b = row >> 13;                       // NA = 2^13
  int c = counts[row], o = offsets[row];
  const float* basep = bonds_out + (size_t)b*NB_*32 + p*4;
  float4 acc = make_float4(0.f, 0.f, 0.f, 0.f);
  int t = 0;
  for (; t + 2 <= c; t += 2){
    int i0 = list[o+t], i1 = list[o+t+1];
    float4 v0 = *(const float4*)(basep + (size_t)i0*32);
    float4 v1 = *(const float4*)(basep + (size_t)i1*32);
    acc.x += v0.x + v1.x; acc.y += v0.y + v1.y;
    acc.z += v0.z + v1.z; acc.w += v0.w + v1.w;
  }
  if (t < c){
    int i0 = list[o+t];
    float4 v0 = *(const float4*)(basep + (size_t)i0*32);
    acc.x += v0.x; acc.y += v0.y; acc.z += v0.z; acc.w += v0.w;
  }
  float inv = 1.0f / (float)c;
  btap[(size_t)row*16 + p*2    ] = packbf(acc.x*inv, acc.y*inv);
  btap[(size_t)row*16 + p*2 + 1] = packbf(acc.z*inv, acc.w*inv);
}

// ---------------- stage 2: atoms MLP via MFMA (64->64->64->32), state folded ----------
// Wv: w1[96][64] @0 | b1 @6144 | w2 @6208 | b2 @10304 | w3 @10368 | b3 @12416
__global__ __launch_bounds__(256, 5) void atoms_kernel(
    const float* __restrict__ atoms,
    const float* __restrict__ Wv,
    const int* __restrict__ counts,
    const unsigned int* __restrict__ btap,   // pre-divided bf16 pairs
    const float* __restrict__ bv,            // effective bias1 [B][64]
    const unsigned short* __restrict__ Wbv,  // swizzled bf16 v-weights
    float* __restrict__ atoms_out,
    float* __restrict__ bondsum,
    float* __restrict__ atomsum)
{
  __shared__ unsigned short hsall[4][1160];
  const int tid  = threadIdx.x;
  const int wave = tid >> 6, lane = tid & 63;
  const int quad = lane >> 4, l16 = lane & 15;
  const int b = blockIdx.y;
  const int arowbase = blockIdx.x*256 + wave*64;
  unsigned short* hwr = &hsall[wave][0] + l16*72;

  int arow[4], cnt[4];
  #pragma unroll
  for (int nt = 0; nt < 4; ++nt){
    arow[nt] = b*NA_ + arowbase + nt*16 + l16;
    cnt[nt]  = counts[arow[nt]];
  }

  float p1[8] = {0,0,0,0,0,0,0,0};   // bondsum partials (feats quad*8+j)
  float p2[8] = {0,0,0,0,0,0,0,0};   // atomsum partials (feats (j>>2)*16+quad*4+(j&3))

  #pragma unroll
  for (int nt = 0; nt < 4; ++nt){
    // ----- layer 1: kt=0 from btap (bf16, pre-divided), kt=1 from atoms (f32) -----
    f32x4 a1[4] = {};
    {
      union { uint4 q; bf16x8 v; } bt;
      bt.q = *(const uint4*)(btap + (size_t)arow[nt]*16 + quad*4);
      float cf = (float)cnt[nt];
      p1[0] += bflo(bt.q.x)*cf; p1[1] += bfhi(bt.q.x)*cf;
      p1[2] += bflo(bt.q.y)*cf; p1[3] += bfhi(bt.q.y)*cf;
      p1[4] += bflo(bt.q.z)*cf; p1[5] += bfhi(bt.q.z)*cf;
      p1[6] += bflo(bt.q.w)*cf; p1[7] += bfhi(bt.q.w)*cf;
      #pragma unroll
      for (int mt = 0; mt < 4; ++mt){
        bf16x8 wf = *(const bf16x8*)(Wbv + ((0*4 + mt)*64 + lane)*8);
        a1[mt] = __builtin_amdgcn_mfma_f32_16x16x32_bf16(wf, bt.v, a1[mt], 0, 0, 0);
      }
    }
    {
      const float* src = atoms + (size_t)arow[nt]*32 + quad*8;
      float4 v0 = *(const float4*)(src);
      float4 v1 = *(const float4*)(src + 4);
      union { bf16x8 v; unsigned int u[4]; } xf;
      xf.u[0] = packbf(v0.x, v0.y);
      xf.u[1] = packbf(v0.z, v0.w);
      xf.u[2] = packbf(v1.x, v1.y);
      xf.u[3] = packbf(v1.z, v1.w);
      #pragma unroll
      for (int mt = 0; mt < 4; ++mt){
        bf16x8 wf = *(const bf16x8*)(Wbv + ((1*4 + mt)*64 + lane)*8);
        a1[mt] = __builtin_amdgcn_mfma_f32_16x16x32_bf16(wf, xf.v, a1[mt], 0, 0, 0);
      }
    }
    lds_fence();   // order vs previous nt's layer-3 LDS reads
    #pragma unroll
    for (int mt = 0; mt < 4; ++mt){
      float4 bias = *(const float4*)(bv + b*64 + mt*16 + quad*4);
      unsigned int lo = packbf(softplus_f(a1[mt][0] + bias.x), softplus_f(a1[mt][1] + bias.y));
      unsigned int hi = packbf(softplus_f(a1[mt][2] + bias.z), softplus_f(a1[mt][3] + bias.w));
      *reinterpret_cast<uint2*>(hwr + mt*16 + quad*4) = make_uint2(lo, hi);
    }
    lds_fence();   // H1 writes before cross-lane H1 reads

    // ----- layer 2 -----
    f32x4 a2[4] = {};
    #pragma unroll
    for (int kt = 0; kt < 2; ++kt){
      bf16x8 hf = *(const bf16x8*)(hwr + kt*32 + quad*8);
      #pragma unroll
      for (int mt = 0; mt < 4; ++mt){
        bf16x8 wf = *(const bf16x8*)(Wbv + 4096 + ((kt*4 + mt)*64 + lane)*8);
        a2[mt] = __builtin_amdgcn_mfma_f32_16x16x32_bf16(wf, hf, a2[mt], 0, 0, 0);
      }
    }
    lds_fence();   // H1 reads before H2 overwrites
    #pragma unroll
    for (int mt = 0; mt < 4; ++mt){
      float4 bias = *(const float4*)(Wv + 10304 + mt*16 + quad*4);
      unsigned int lo = packbf(softplus_f(a2[mt][0] + bias.x), softplus_f(a2[mt][1] + bias.y));
      unsigned int hi = packbf(softplus_f(a2[mt][2] + bias.z), softplus_f(a2[mt][3] + bias.w));
      *reinterpret_cast<uint2*>(hwr + mt*16 + quad*4) = make_uint2(lo, hi);
    }
    lds_fence();   // H2 writes before cross-lane H2 reads

    // ----- layer 3 -----
    f32x4 a3[2] = {};
    #pragma unroll
    for (int kt = 0; kt < 2; ++kt){
      bf16x8 hf = *(const bf16x8*)(hwr + kt*32 + quad*8);
      #pragma unroll
      for (int mt = 0; mt < 2; ++mt){
        bf16x8 wf = *(const bf16x8*)(Wbv + 8192 + ((kt*2 + mt)*64 + lane)*8);
        a3[mt] = __builtin_amdgcn_mfma_f32_16x16x32_bf16(wf, hf, a3[mt], 0, 0, 0);
      }
    }
    #pragma unroll
    for (int mt = 0; mt < 2; ++mt){
      float4 bias = *(const float4*)(Wv + 12416 + mt*16 + quad*4);
      float4 o;
      o.x = softplus_f(a3[mt][0] + bias.x);
      o.y = softplus_f(a3[mt][1] + bias.y);
      o.z = softplus_f(a3[mt][2] + bias.z);
      o.w = softplus_f(a3[mt][3] + bias.w);
      p2[mt*4+0] += o.x; p2[mt*4+1] += o.y; p2[mt*4+2] += o.z; p2[mt*4+3] += o.w;
      *reinterpret_cast<float4*>(atoms_out + (size_t)arow[nt]*32 + mt*16 + quad*4) = o;
    }
  }

  // reduce partials across the 16 lanes of each quad-group, one atomic per feat
  #pragma unroll
  for (int j = 0; j < 8; ++j){
    float v = p1[j];
    v += __shfl_xor(v, 1); v += __shfl_xor(v, 2);
    v += __shfl_xor(v, 4); v += __shfl_xor(v, 8);
    if (l16 == 0) unsafeAtomicAdd(&bondsum[b*32 + quad*8 + j], v);
    float w = p2[j];
    w += __shfl_xor(w, 1); w += __shfl_xor(w, 2);
    w += __shfl_xor(w, 4); w += __shfl_xor(w, 8);
    if (l16 == 0) unsafeAtomicAdd(&atomsum[b*32 + (j>>2)*16 + quad*4 + (j&3)], w);
  }
}

// ---------------- stage 3: state MLP (96->64->64->32), 4 rows ----------------
__global__ __launch_bounds__(256) void state_kernel(
    const float* __restrict__ state,
    const float* __restrict__ W,
    const float* __restrict__ bondsum,
    const float* __restrict__ atomsum,
    float* __restrict__ state_out)
{
  __shared__ float uin[4][96];
  __shared__ float h1s[4][64];
  __shared__ float h2s[4][64];
  const int tid = threadIdx.x;
  const int b = tid >> 6;
  const int j = tid & 63;
  if (j < 32){
    uin[b][j]      = bondsum[b*32 + j] * (1.0f/(float)NB_);
    uin[b][32 + j] = atomsum[b*32 + j] * (1.0f/(float)NA_);
    uin[b][64 + j] = state[(size_t)b*32 + j];
  }
  __syncthreads();
  float a1 = W[6144 + j];
  for (int k = 0; k < 96; ++k) a1 = fmaf(uin[b][k], W[k*64 + j], a1);
  h1s[b][j] = softplus_f(a1);
  __syncthreads();
  float a2 = W[10304 + j];
  for (int k = 0; k < 64; ++k) a2 = fmaf(h1s[b][k], W[6208 + k*64 + j], a2);
  h2s[b][j] = softplus_f(a2);
  __syncthreads();
  if (j < 32){
    float a3 = W[12416 + j];
    for (int k = 0; k < 64; ++k) a3 = fmaf(h2s[b][k], W[10368 + k*32 + j], a3);
    state_out[b*32 + j] = softplus_f(a3);
  }
}

// ---------------- launcher ----------------
// ws (4-byte units): counts[32768]@0 | offsets@32768 | Wbv u16[10240]@65536 (5120 dw) |
//   list[1048576]@98304 | btap[524288]@1146880 | bondsum[128]@1671168 | atomsum[128]@1671296 |
//   W f32[39392]@1671424 | Wb u16[14336]@1710816 (7168 dw) | be[256]@1717984 | bv[256]@1718240
// Aliases: partials@list (dead before fill writes list); bases@btap (dead before gather).
extern "C" void kernel_launch(void* const* d_in, const int* in_sizes, int n_in,
                              void* d_out, int out_size, void* d_ws, size_t ws_size,
                              hipStream_t stream)
{
  (void)in_sizes; (void)n_in; (void)out_size; (void)ws_size;
  const float* bonds = (const float*)d_in[0];
  const int*   ba1   = (const int*)d_in[1];
  const int*   ba2   = (const int*)d_in[2];
  const float* atoms = (const float*)d_in[3];
  const float* state = (const float*)d_in[4];

  int*          counts  = (int*)d_ws;
  int*          offsets = counts + 32768;
  unsigned short* Wbv   = (unsigned short*)((unsigned int*)d_ws + 65536);
  int*          list    = counts + 98304;
  unsigned int* btap    = (unsigned int*)d_ws + 1146880;
  float*        bondsum = (float*)d_ws + 1671168;
  float*        atomsum = (float*)d_ws + 1671296;
  float*        W       = (float*)d_ws + 1671424;
  unsigned short* Wb    = (unsigned short*)((unsigned int*)d_ws + 1710816);
  float*        be      = (float*)d_ws + 1717984;
  float*        bv      = (float*)d_ws + 1718240;

  int* partials = list;           // dead before fill overwrites list
  int* bases    = (int*)btap;     // dead before gather overwrites btap

  hipMemsetAsync(bondsum, 0, 256 * sizeof(float), stream);

  WPtrs wp;
  for (int s = 0; s < 18; ++s) wp.p[s] = (const float*)d_in[5 + s];
  prep_kernel<<<154, 256, 0, stream>>>(wp, W);
  biaseff_kernel<<<1, 512, 0, stream>>>(state, W, be, bv);
  swizzle_kernel<<<96, 256, 0, stream>>>((const float*)d_in[5], (const float*)d_in[7],
                                         (const float*)d_in[9],
                                         (const float*)d_in[11], (const float*)d_in[13],
                                         (const float*)d_in[15], Wb, Wbv);

  // CSR build — counting sort with LDS histograms
  hist_lds_kernel<<<64, 1024, 0, stream>>>(ba1, partials);
  reduce_kernel<<<128, 256, 0, stream>>>(partials, counts);
  scan_kernel<<<1, 1024, 0, stream>>>(counts, offsets);
  base_kernel<<<128, 256, 0, stream>>>(offsets, partials, bases);
  fill_lds_kernel<<<64, 1024, 0, stream>>>(ba1, bases, list);

  float* out_bonds = (float*)d_out;
  float* out_atoms = out_bonds + (size_t)B_*NB_*32;
  float* out_state = out_atoms + (size_t)B_*NA_*32;

  bonds_kernel<<<dim3(NB_/256, B_), 256, 0, stream>>>(bonds, ba1, ba2, atoms,
                                                      W, Wb, be, out_bonds);
  gather_kernel<<<(B_*NA_*8)/256, 256, 0, stream>>>(counts, offsets, list, out_bonds, btap);
  atoms_kernel<<<dim3(NA_/256, B_), 256, 0, stream>>>(atoms, W + 14496,
                                                      counts, btap, bv, Wbv, out_atoms,
                                                      bondsum, atomsum);
  state_kernel<<<1, 256, 0, stream>>>(state, W + 26944, bondsum, atomsum, out_state);
}

// Round 5
// 527.746 us; speedup vs baseline: 1.2398x; 1.0283x over previous
//
#include <hip/hip_runtime.h>

#define B_   4
#define NB_  262144
#define NA_  8192
#define NB_SHIFT 18

typedef short bf16x8 __attribute__((ext_vector_type(8)));
typedef float f32x4  __attribute__((ext_vector_type(4)));

// ---------------- helpers ----------------
__device__ __forceinline__ float bflo(unsigned int u){ return __uint_as_float(u << 16); }
__device__ __forceinline__ float bfhi(unsigned int u){ return __uint_as_float(u & 0xffff0000u); }
__device__ __forceinline__ unsigned short f2bf(float f){
  unsigned int u = __float_as_uint(f);
  u += 0x7fffu + ((u >> 16) & 1u);   // round-to-nearest-even
  return (unsigned short)(u >> 16);
}
// HW packed f32->bf16 (RNE, same as f2bf) — 1 instr
__device__ __forceinline__ unsigned int packbf(float a, float b){
  unsigned int r;
  asm("v_cvt_pk_bf16_f32 %0, %1, %2" : "=v"(r) : "v"(a), "v"(b));
  return r;
}
__device__ __forceinline__ float softplus_f(float v){
  return fmaxf(v, 0.0f) + __logf(1.0f + __expf(-fabsf(v)));
}
// memory-op ordering fence for intra-wave cross-lane LDS communication.
// memory clobber: no memory op may cross (IR+MIR); wave_barrier: code-motion pin.
// NOTE: no sched_barrier(0) — round 4 showed it destroys ILP/regalloc (VGPR 48,
// serialized gather chains, +80MB L2 traffic).
__device__ __forceinline__ void lds_fence(){
  asm volatile("" ::: "memory");
  __builtin_amdgcn_wave_barrier();
}

// ---------------- weight prep: concat the 18 f32 arrays ----------------
struct WPtrs { const float* p[18]; };

__global__ __launch_bounds__(256) void prep_kernel(WPtrs wp, float* __restrict__ W){
  int i = blockIdx.x * 256 + threadIdx.x;
  if (i >= 39392) return;
  int idx = i;
  const int sizes[18] = {8192,64,4096,64,2048,32,
                         6144,64,4096,64,2048,32,
                         6144,64,4096,64,2048,32};
  #pragma unroll
  for (int s = 0; s < 18; ++s){
    if (idx < sizes[s]){ W[i] = wp.p[s][idx]; return; }
    idx -= sizes[s];
  }
}

// ---------------- effective layer-1 biases: fold the (per-batch constant) state term ----
__global__ __launch_bounds__(512) void biaseff_kernel(const float* __restrict__ state,
                                                      const float* __restrict__ W,
                                                      float* __restrict__ be,
                                                      float* __restrict__ bv){
  int t = threadIdx.x;
  int b = (t >> 6) & 3, j = t & 63;
  const float* st = state + b*32;
  if (t < 256){
    float a = W[8192 + j];
    #pragma unroll
    for (int k = 0; k < 32; ++k) a = fmaf(st[k], W[(96+k)*64 + j], a);
    be[b*64 + j] = a;
  } else {
    float a = W[14496 + 6144 + j];
    #pragma unroll
    for (int k = 0; k < 32; ++k) a = fmaf(st[k], W[14496 + (64+k)*64 + j], a);
    bv[b*64 + j] = a;
  }
}

// ---------------- swizzle e- and v-MLP weights into MFMA A-fragment order (bf16) -------
// lane holds frag[k = quad*8 + j][col = lane&15]  (W^T-as-A == W-as-B element-for-element)
__global__ __launch_bounds__(256) void swizzle_kernel(
    const float* __restrict__ ew1, const float* __restrict__ ew2,
    const float* __restrict__ ew3,
    const float* __restrict__ vw1, const float* __restrict__ vw2,
    const float* __restrict__ vw3,
    unsigned short* __restrict__ Wb, unsigned short* __restrict__ Wbv){
  int i = blockIdx.x*256 + threadIdx.x;
  if (i >= 24576) return;
  int j = i & 7, lane = (i >> 3) & 63;
  int quad = lane >> 4, l16 = lane & 15;
  int krow = quad*8 + j;
  float v;
  if (i < 14336){
    if (i < 8192){
      int g = i >> 9;  int mt = g & 3, kt = g >> 2;
      v = ew1[(kt*32 + krow)*64 + mt*16 + l16];
    } else if (i < 12288){
      int g = (i - 8192) >> 9;  int mt = g & 3, kt = g >> 2;
      v = ew2[(kt*32 + krow)*64 + mt*16 + l16];
    } else {
      int g = (i - 12288) >> 9;  int mt = g & 1, kt = g >> 1;
      v = ew3[(kt*32 + krow)*32 + mt*16 + l16];
    }
    Wb[i] = f2bf(v);
  } else {
    int o = i - 14336;
    if (o < 4096){
      int g = o >> 9;  int mt = g & 3, kt = g >> 2;     // kt<2: rows 0..63 (state folded)
      v = vw1[(kt*32 + krow)*64 + mt*16 + l16];
    } else if (o < 8192){
      int g = (o - 4096) >> 9;  int mt = g & 3, kt = g >> 2;
      v = vw2[(kt*32 + krow)*64 + mt*16 + l16];
    } else {
      int g = (o - 8192) >> 9;  int mt = g & 1, kt = g >> 1;
      v = vw3[(kt*32 + krow)*32 + mt*16 + l16];
    }
    Wbv[o] = f2bf(v);
  }
}

// ---------------- CSR build: LDS-histogram counting sort ----------------
__global__ __launch_bounds__(1024) void hist_lds_kernel(const int* __restrict__ ba1,
                                                        int* __restrict__ partials){
  __shared__ int lh[NA_];
  const int tid = threadIdx.x;
  const int blk = blockIdx.x;
  const int b = blk >> 4;
  const size_t base = (size_t)b*NB_ + (size_t)(blk & 15)*16384;
  #pragma unroll
  for (int i = tid; i < NA_; i += 1024) lh[i] = 0;
  __syncthreads();
  #pragma unroll
  for (int it = 0; it < 16; ++it)
    atomicAdd(&lh[ba1[base + it*1024 + tid]], 1);
  __syncthreads();
  #pragma unroll
  for (int i = tid; i < NA_; i += 1024) partials[blk*NA_ + i] = lh[i];
}

__global__ __launch_bounds__(256) void reduce_kernel(const int* __restrict__ partials,
                                                     int* __restrict__ counts){
  int t = blockIdx.x*256 + threadIdx.x;     // [0, 32768)
  int b = t >> 13, aa = t & (NA_-1);
  int s = 0;
  #pragma unroll
  for (int lb = 0; lb < 16; ++lb) s += partials[(b*16 + lb)*NA_ + aa];
  counts[t] = s;
}

__global__ __launch_bounds__(1024) void scan_kernel(const int* __restrict__ counts,
                                                    int* __restrict__ offsets){
  __shared__ int s[1024];
  const int tid = threadIdx.x;
  const int base = tid * 32;
  int local[32]; int sum = 0;
  #pragma unroll
  for (int i = 0; i < 32; ++i){ local[i] = counts[base + i]; sum += local[i]; }
  s[tid] = sum;
  __syncthreads();
  for (int off = 1; off < 1024; off <<= 1){
    int v = (tid >= off) ? s[tid - off] : 0;
    __syncthreads();
    s[tid] += v;
    __syncthreads();
  }
  int run = s[tid] - sum;
  #pragma unroll
  for (int i = 0; i < 32; ++i){
    offsets[base + i] = run; run += local[i];
  }
}

__global__ __launch_bounds__(256) void base_kernel(const int* __restrict__ offsets,
                                                   const int* __restrict__ partials,
                                                   int* __restrict__ bases){
  int t = blockIdx.x*256 + threadIdx.x;     // [0, 32768)
  int b = t >> 13, aa = t & (NA_-1);
  int run = offsets[t];
  #pragma unroll
  for (int lb = 0; lb < 16; ++lb){
    int g = (b*16 + lb)*NA_ + aa;
    bases[g] = run; run += partials[g];
  }
}

__global__ __launch_bounds__(1024) void fill_lds_kernel(const int* __restrict__ ba1,
                                                        const int* __restrict__ bases,
                                                        int* __restrict__ list){
  __shared__ int lh[NA_];
  const int tid = threadIdx.x;
  const int blk = blockIdx.x;
  const int b = blk >> 4;
  const size_t base = (size_t)b*NB_ + (size_t)(blk & 15)*16384;
  #pragma unroll
  for (int i = tid; i < NA_; i += 1024) lh[i] = 0;
  __syncthreads();
  #pragma unroll
  for (int it = 0; it < 16; ++it){
    int idx = it*1024 + tid;
    int a = ba1[base + idx];
    int rank = atomicAdd(&lh[a], 1);
    list[bases[blk*NA_ + a] + rank] = (int)((base + idx) & (NB_ - 1));
  }
}

// ---------------- stage 1: bonds MLP via MFMA, nt-sequential, full input prefetch ------
// All 12 gather vectors loaded+packed BEFORE the first fence: one latency exposure,
// not four serialized ones. LDS 16x72 shorts/wave.
__global__ __launch_bounds__(256, 4) void bonds_kernel(
    const float* __restrict__ bonds,
    const int* __restrict__ ba1,
    const int* __restrict__ ba2,
    const float* __restrict__ atoms,
    const float* __restrict__ W,            // f32 concat (biases 2,3)
    const unsigned short* __restrict__ Wb,  // swizzled bf16 e-weights
    const float* __restrict__ be,           // effective bias1 [B][64]
    float* __restrict__ bonds_out)
{
  __shared__ unsigned short hsall[4][1160];   // 16*72 used, +8 pad
  const int tid  = threadIdx.x;
  const int wave = tid >> 6, lane = tid & 63;
  const int quad = lane >> 4, l16 = lane & 15;
  const int b = blockIdx.y;
  const int rowbase = blockIdx.x*256 + wave*64;
  unsigned short* hwr = &hsall[wave][0] + l16*72;   // this lane's LDS row

  int r[4], g1[4], g2[4];
  #pragma unroll
  for (int nt = 0; nt < 4; ++nt){
    r[nt]  = rowbase + nt*16 + l16;
    g1[nt] = ba1[(size_t)b*NB_ + r[nt]];
    g2[nt] = ba2[(size_t)b*NB_ + r[nt]];
  }

  // prefetch + pack all inputs (12 x 32B loads overlap in flight)
  unsigned int xin[4][3][4];
  #pragma unroll
  for (int nt = 0; nt < 4; ++nt){
    #pragma unroll
    for (int kt = 0; kt < 3; ++kt){
      const float* src;
      if      (kt == 0) src = atoms + ((size_t)b*NA_ + g1[nt])*32 + quad*8;
      else if (kt == 1) src = atoms + ((size_t)b*NA_ + g2[nt])*32 + quad*8;
      else              src = bonds + ((size_t)b*NB_ + r[nt])*32 + quad*8;
      float4 v0 = *(const float4*)(src);
      float4 v1 = *(const float4*)(src + 4);
      xin[nt][kt][0] = packbf(v0.x, v0.y);
      xin[nt][kt][1] = packbf(v0.z, v0.w);
      xin[nt][kt][2] = packbf(v1.x, v1.y);
      xin[nt][kt][3] = packbf(v1.z, v1.w);
    }
  }

  #pragma unroll
  for (int nt = 0; nt < 4; ++nt){
    // ----- layer 1: [64 feat][96 k] x [96 k][16 bond] -----
    f32x4 a1[4] = {};
    #pragma unroll
    for (int kt = 0; kt < 3; ++kt){
      union { bf16x8 v; unsigned int u[4]; } xf;
      xf.u[0] = xin[nt][kt][0]; xf.u[1] = xin[nt][kt][1];
      xf.u[2] = xin[nt][kt][2]; xf.u[3] = xin[nt][kt][3];
      #pragma unroll
      for (int mt = 0; mt < 4; ++mt){
        bf16x8 wf = *(const bf16x8*)(Wb + ((kt*4 + mt)*64 + lane)*8);
        a1[mt] = __builtin_amdgcn_mfma_f32_16x16x32_bf16(wf, xf.v, a1[mt], 0, 0, 0);
      }
    }
    lds_fence();   // order vs previous nt's layer-3 LDS reads
    #pragma unroll
    for (int mt = 0; mt < 4; ++mt){
      float4 bias = *(const float4*)(be + b*64 + mt*16 + quad*4);
      unsigned int lo = packbf(softplus_f(a1[mt][0] + bias.x), softplus_f(a1[mt][1] + bias.y));
      unsigned int hi = packbf(softplus_f(a1[mt][2] + bias.z), softplus_f(a1[mt][3] + bias.w));
      *reinterpret_cast<uint2*>(hwr + mt*16 + quad*4) = make_uint2(lo, hi);
    }
    lds_fence();   // H1 writes before cross-lane H1 reads

    // ----- layer 2: [64][64] -----
    f32x4 a2[4] = {};
    #pragma unroll
    for (int kt = 0; kt < 2; ++kt){
      bf16x8 hf = *(const bf16x8*)(hwr + kt*32 + quad*8);
      #pragma unroll
      for (int mt = 0; mt < 4; ++mt){
        bf16x8 wf = *(const bf16x8*)(Wb + 8192 + ((kt*4 + mt)*64 + lane)*8);
        a2[mt] = __builtin_amdgcn_mfma_f32_16x16x32_bf16(wf, hf, a2[mt], 0, 0, 0);
      }
    }
    lds_fence();   // H1 reads before H2 overwrites
    #pragma unroll
    for (int mt = 0; mt < 4; ++mt){
      float4 bias = *(const float4*)(W + 12352 + mt*16 + quad*4);
      unsigned int lo = packbf(softplus_f(a2[mt][0] + bias.x), softplus_f(a2[mt][1] + bias.y));
      unsigned int hi = packbf(softplus_f(a2[mt][2] + bias.z), softplus_f(a2[mt][3] + bias.w));
      *reinterpret_cast<uint2*>(hwr + mt*16 + quad*4) = make_uint2(lo, hi);
    }
    lds_fence();   // H2 writes before cross-lane H2 reads

    // ----- layer 3: [32][64] -----
    f32x4 a3[2] = {};
    #pragma unroll
    for (int kt = 0; kt < 2; ++kt){
      bf16x8 hf = *(const bf16x8*)(hwr + kt*32 + quad*8);
      #pragma unroll
      for (int mt = 0; mt < 2; ++mt){
        bf16x8 wf = *(const bf16x8*)(Wb + 12288 + ((kt*2 + mt)*64 + lane)*8);
        a3[mt] = __builtin_amdgcn_mfma_f32_16x16x32_bf16(wf, hf, a3[mt], 0, 0, 0);
      }
    }
    // compute both halves, then write the full 128B row with adjacent stores
    float4 o0, o1;
    {
      float4 bias = *(const float4*)(W + 14464 + quad*4);
      o0.x = softplus_f(a3[0][0] + bias.x);
      o0.y = softplus_f(a3[0][1] + bias.y);
      o0.z = softplus_f(a3[0][2] + bias.z);
      o0.w = softplus_f(a3[0][3] + bias.w);
    }
    {
      float4 bias = *(const float4*)(W + 14464 + 16 + quad*4);
      o1.x = softplus_f(a3[1][0] + bias.x);
      o1.y = softplus_f(a3[1][1] + bias.y);
      o1.z = softplus_f(a3[1][2] + bias.z);
      o1.w = softplus_f(a3[1][3] + bias.w);
    }
    float* outp = bonds_out + ((size_t)b*NB_ + r[nt])*32 + quad*4;
    *reinterpret_cast<float4*>(outp)      = o0;
    *reinterpret_cast<float4*>(outp + 16) = o1;
  }
}

// ---------------- gather: mean of bonds_out rows per atom -> packed bf16 (pre-divided) --
__global__ __launch_bounds__(256) void gather_kernel(
    const int* __restrict__ counts,
    const int* __restrict__ offsets,
    const int* __restrict__ list,
    const float* __restrict__ bonds_out,
    unsigned int* __restrict__ btap)
{
  int i = blockIdx.x*256 + threadIdx.x;   // [0, B*NA*8)
  int p = i & 7;
  int row = i >> 3;                        // b*NA + atom
  int b = row >> 13;                       // NA = 2^13
  int c = counts[row], o = offsets[row];
  const float* basep = bonds_out + (size_t)b*NB_*32 + p*4;
  float4 acc = make_float4(0.f, 0.f, 0.f, 0.f);
  int t = 0;
  for (; t + 2 <= c; t += 2){
    int i0 = list[o+t], i1 = list[o+t+1];
    float4 v0 = *(const float4*)(basep + (size_t)i0*32);
    float4 v1 = *(const float4*)(basep + (size_t)i1*32);
    acc.x += v0.x + v1.x; acc.y += v0.y + v1.y;
    acc.z += v0.z + v1.z; acc.w += v0.w + v1.w;
  }
  if (t < c){
    int i0 = list[o+t];
    float4 v0 = *(const float4*)(basep + (size_t)i0*32);
    acc.x += v0.x; acc.y += v0.y; acc.z += v0.z; acc.w += v0.w;
  }
  float inv = 1.0f / (float)c;
  btap[(size_t)row*16 + p*2    ] = packbf(acc.x*inv, acc.y*inv);
  btap[(size_t)row*16 + p*2 + 1] = packbf(acc.z*inv, acc.w*inv);
}

// ---------------- stage 2: atoms MLP via MFMA (64->64->64->32), state folded ----------
// Wv: w1[96][64] @0 | b1 @6144 | w2 @6208 | b2 @10304 | w3 @10368 | b3 @12416
__global__ __launch_bounds__(256, 4) void atoms_kernel(
    const float* __restrict__ atoms,
    const float* __restrict__ Wv,
    const int* __restrict__ counts,
    const unsigned int* __restrict__ btap,   // pre-divided bf16 pairs
    const float* __restrict__ bv,            // effective bias1 [B][64]
    const unsigned short* __restrict__ Wbv,  // swizzled bf16 v-weights
    float* __restrict__ atoms_out,
    float* __restrict__ bondsum,
    float* __restrict__ atomsum)
{
  __shared__ unsigned short hsall[4][1160];
  const int tid  = threadIdx.x;
  const int wave = tid >> 6, lane = tid & 63;
  const int quad = lane >> 4, l16 = lane & 15;
  const int b = blockIdx.y;
  const int arowbase = blockIdx.x*256 + wave*64;
  unsigned short* hwr = &hsall[wave][0] + l16*72;

  int arow[4], cnt[4];
  #pragma unroll
  for (int nt = 0; nt < 4; ++nt){
    arow[nt] = b*NA_ + arowbase + nt*16 + l16;
    cnt[nt]  = counts[arow[nt]];
  }

  // prefetch all inputs (btap + atoms rows) before any fence
  uint4 bt[4];
  unsigned int axin[4][4];
  #pragma unroll
  for (int nt = 0; nt < 4; ++nt){
    bt[nt] = *(const uint4*)(btap + (size_t)arow[nt]*16 + quad*4);
    const float* src = atoms + (size_t)arow[nt]*32 + quad*8;
    float4 v0 = *(const float4*)(src);
    float4 v1 = *(const float4*)(src + 4);
    axin[nt][0] = packbf(v0.x, v0.y);
    axin[nt][1] = packbf(v0.z, v0.w);
    axin[nt][2] = packbf(v1.x, v1.y);
    axin[nt][3] = packbf(v1.z, v1.w);
  }

  float p1[8] = {0,0,0,0,0,0,0,0};   // bondsum partials (feats quad*8+j)
  float p2[8] = {0,0,0,0,0,0,0,0};   // atomsum partials (feats (j>>2)*16+quad*4+(j&3))

  #pragma unroll
  for (int nt = 0; nt < 4; ++nt){
    // ----- layer 1: kt=0 from btap (bf16, pre-divided), kt=1 from atoms -----
    f32x4 a1[4] = {};
    {
      union { uint4 q; bf16x8 v; } btv; btv.q = bt[nt];
      float cf = (float)cnt[nt];
      p1[0] += bflo(bt[nt].x)*cf; p1[1] += bfhi(bt[nt].x)*cf;
      p1[2] += bflo(bt[nt].y)*cf; p1[3] += bfhi(bt[nt].y)*cf;
      p1[4] += bflo(bt[nt].z)*cf; p1[5] += bfhi(bt[nt].z)*cf;
      p1[6] += bflo(bt[nt].w)*cf; p1[7] += bfhi(bt[nt].w)*cf;
      #pragma unroll
      for (int mt = 0; mt < 4; ++mt){
        bf16x8 wf = *(const bf16x8*)(Wbv + ((0*4 + mt)*64 + lane)*8);
        a1[mt] = __builtin_amdgcn_mfma_f32_16x16x32_bf16(wf, btv.v, a1[mt], 0, 0, 0);
      }
    }
    {
      union { bf16x8 v; unsigned int u[4]; } xf;
      xf.u[0] = axin[nt][0]; xf.u[1] = axin[nt][1];
      xf.u[2] = axin[nt][2]; xf.u[3] = axin[nt][3];
      #pragma unroll
      for (int mt = 0; mt < 4; ++mt){
        bf16x8 wf = *(const bf16x8*)(Wbv + ((1*4 + mt)*64 + lane)*8);
        a1[mt] = __builtin_amdgcn_mfma_f32_16x16x32_bf16(wf, xf.v, a1[mt], 0, 0, 0);
      }
    }
    lds_fence();   // order vs previous nt's layer-3 LDS reads
    #pragma unroll
    for (int mt = 0; mt < 4; ++mt){
      float4 bias = *(const float4*)(bv + b*64 + mt*16 + quad*4);
      unsigned int lo = packbf(softplus_f(a1[mt][0] + bias.x), softplus_f(a1[mt][1] + bias.y));
      unsigned int hi = packbf(softplus_f(a1[mt][2] + bias.z), softplus_f(a1[mt][3] + bias.w));
      *reinterpret_cast<uint2*>(hwr + mt*16 + quad*4) = make_uint2(lo, hi);
    }
    lds_fence();   // H1 writes before cross-lane H1 reads

    // ----- layer 2 -----
    f32x4 a2[4] = {};
    #pragma unroll
    for (int kt = 0; kt < 2; ++kt){
      bf16x8 hf = *(const bf16x8*)(hwr + kt*32 + quad*8);
      #pragma unroll
      for (int mt = 0; mt < 4; ++mt){
        bf16x8 wf = *(const bf16x8*)(Wbv + 4096 + ((kt*4 + mt)*64 + lane)*8);
        a2[mt] = __builtin_amdgcn_mfma_f32_16x16x32_bf16(wf, hf, a2[mt], 0, 0, 0);
      }
    }
    lds_fence();   // H1 reads before H2 overwrites
    #pragma unroll
    for (int mt = 0; mt < 4; ++mt){
      float4 bias = *(const float4*)(Wv + 10304 + mt*16 + quad*4);
      unsigned int lo = packbf(softplus_f(a2[mt][0] + bias.x), softplus_f(a2[mt][1] + bias.y));
      unsigned int hi = packbf(softplus_f(a2[mt][2] + bias.z), softplus_f(a2[mt][3] + bias.w));
      *reinterpret_cast<uint2*>(hwr + mt*16 + quad*4) = make_uint2(lo, hi);
    }
    lds_fence();   // H2 writes before cross-lane H2 reads

    // ----- layer 3 -----
    f32x4 a3[2] = {};
    #pragma unroll
    for (int kt = 0; kt < 2; ++kt){
      bf16x8 hf = *(const bf16x8*)(hwr + kt*32 + quad*8);
      #pragma unroll
      for (int mt = 0; mt < 2; ++mt){
        bf16x8 wf = *(const bf16x8*)(Wbv + 8192 + ((kt*2 + mt)*64 + lane)*8);
        a3[mt] = __builtin_amdgcn_mfma_f32_16x16x32_bf16(wf, hf, a3[mt], 0, 0, 0);
      }
    }
    float4 o0, o1;
    {
      float4 bias = *(const float4*)(Wv + 12416 + quad*4);
      o0.x = softplus_f(a3[0][0] + bias.x);
      o0.y = softplus_f(a3[0][1] + bias.y);
      o0.z = softplus_f(a3[0][2] + bias.z);
      o0.w = softplus_f(a3[0][3] + bias.w);
    }
    {
      float4 bias = *(const float4*)(Wv + 12416 + 16 + quad*4);
      o1.x = softplus_f(a3[1][0] + bias.x);
      o1.y = softplus_f(a3[1][1] + bias.y);
      o1.z = softplus_f(a3[1][2] + bias.z);
      o1.w = softplus_f(a3[1][3] + bias.w);
    }
    p2[0] += o0.x; p2[1] += o0.y; p2[2] += o0.z; p2[3] += o0.w;
    p2[4] += o1.x; p2[5] += o1.y; p2[6] += o1.z; p2[7] += o1.w;
    float* outp = atoms_out + (size_t)arow[nt]*32 + quad*4;
    *reinterpret_cast<float4*>(outp)      = o0;
    *reinterpret_cast<float4*>(outp + 16) = o1;
  }

  // reduce partials across the 16 lanes of each quad-group, one atomic per feat
  #pragma unroll
  for (int j = 0; j < 8; ++j){
    float v = p1[j];
    v += __shfl_xor(v, 1); v += __shfl_xor(v, 2);
    v += __shfl_xor(v, 4); v += __shfl_xor(v, 8);
    if (l16 == 0) unsafeAtomicAdd(&bondsum[b*32 + quad*8 + j], v);
    float w = p2[j];
    w += __shfl_xor(w, 1); w += __shfl_xor(w, 2);
    w += __shfl_xor(w, 4); w += __shfl_xor(w, 8);
    if (l16 == 0) unsafeAtomicAdd(&atomsum[b*32 + (j>>2)*16 + quad*4 + (j&3)], w);
  }
}

// ---------------- stage 3: state MLP (96->64->64->32), 4 rows ----------------
__global__ __launch_bounds__(256) void state_kernel(
    const float* __restrict__ state,
    const float* __restrict__ W,
    const float* __restrict__ bondsum,
    const float* __restrict__ atomsum,
    float* __restrict__ state_out)
{
  __shared__ float uin[4][96];
  __shared__ float h1s[4][64];
  __shared__ float h2s[4][64];
  const int tid = threadIdx.x;
  const int b = tid >> 6;
  const int j = tid & 63;
  if (j < 32){
    uin[b][j]      = bondsum[b*32 + j] * (1.0f/(float)NB_);
    uin[b][32 + j] = atomsum[b*32 + j] * (1.0f/(float)NA_);
    uin[b][64 + j] = state[(size_t)b*32 + j];
  }
  __syncthreads();
  float a1 = W[6144 + j];
  for (int k = 0; k < 96; ++k) a1 = fmaf(uin[b][k], W[k*64 + j], a1);
  h1s[b][j] = softplus_f(a1);
  __syncthreads();
  float a2 = W[10304 + j];
  for (int k = 0; k < 64; ++k) a2 = fmaf(h1s[b][k], W[6208 + k*64 + j], a2);
  h2s[b][j] = softplus_f(a2);
  __syncthreads();
  if (j < 32){
    float a3 = W[12416 + j];
    for (int k = 0; k < 64; ++k) a3 = fmaf(h2s[b][k], W[10368 + k*32 + j], a3);
    state_out[b*32 + j] = softplus_f(a3);
  }
}

// ---------------- launcher ----------------
// ws (4-byte units): counts[32768]@0 | offsets@32768 | Wbv u16[10240]@65536 (5120 dw) |
//   list[1048576]@98304 | btap[524288]@1146880 | bondsum[128]@1671168 | atomsum[128]@1671296 |
//   W f32[39392]@1671424 | Wb u16[14336]@1710816 (7168 dw) | be[256]@1717984 | bv[256]@1718240
// Aliases: partials@list (dead before fill writes list); bases@btap (dead before gather).
extern "C" void kernel_launch(void* const* d_in, const int* in_sizes, int n_in,
                              void* d_out, int out_size, void* d_ws, size_t ws_size,
                              hipStream_t stream)
{
  (void)in_sizes; (void)n_in; (void)out_size; (void)ws_size;
  const float* bonds = (const float*)d_in[0];
  const int*   ba1   = (const int*)d_in[1];
  const int*   ba2   = (const int*)d_in[2];
  const float* atoms = (const float*)d_in[3];
  const float* state = (const float*)d_in[4];

  int*          counts  = (int*)d_ws;
  int*          offsets = counts + 32768;
  unsigned short* Wbv   = (unsigned short*)((unsigned int*)d_ws + 65536);
  int*          list    = counts + 98304;
  unsigned int* btap    = (unsigned int*)d_ws + 1146880;
  float*        bondsum = (float*)d_ws + 1671168;
  float*        atomsum = (float*)d_ws + 1671296;
  float*        W       = (float*)d_ws + 1671424;
  unsigned short* Wb    = (unsigned short*)((unsigned int*)d_ws + 1710816);
  float*        be      = (float*)d_ws + 1717984;
  float*        bv      = (float*)d_ws + 1718240;

  int* partials = list;           // dead before fill overwrites list
  int* bases    = (int*)btap;     // dead before gather overwrites btap

  hipMemsetAsync(bondsum, 0, 256 * sizeof(float), stream);

  WPtrs wp;
  for (int s = 0; s < 18; ++s) wp.p[s] = (const float*)d_in[5 + s];
  prep_kernel<<<154, 256, 0, stream>>>(wp, W);
  biaseff_kernel<<<1, 512, 0, stream>>>(state, W, be, bv);
  swizzle_kernel<<<96, 256, 0, stream>>>((const float*)d_in[5], (const float*)d_in[7],
                                         (const float*)d_in[9],
                                         (const float*)d_in[11], (const float*)d_in[13],
                                         (const float*)d_in[15], Wb, Wbv);

  // CSR build — counting sort with LDS histograms
  hist_lds_kernel<<<64, 1024, 0, stream>>>(ba1, partials);
  reduce_kernel<<<128, 256, 0, stream>>>(partials, counts);
  scan_kernel<<<1, 1024, 0, stream>>>(counts, offsets);
  base_kernel<<<128, 256, 0, stream>>>(offsets, partials, bases);
  fill_lds_kernel<<<64, 1024, 0, stream>>>(ba1, bases, list);

  float* out_bonds = (float*)d_out;
  float* out_atoms = out_bonds + (size_t)B_*NB_*32;
  float* out_state = out_atoms + (size_t)B_*NA_*32;

  bonds_kernel<<<dim3(NB_/256, B_), 256, 0, stream>>>(bonds, ba1, ba2, atoms,
                                                      W, Wb, be, out_bonds);
  gather_kernel<<<(B_*NA_*8)/256, 256, 0, stream>>>(counts, offsets, list, out_bonds, btap);
  atoms_kernel<<<dim3(NA_/256, B_), 256, 0, stream>>>(atoms, W + 14496,
                                                      counts, btap, bv, Wbv, out_atoms,
                                                      bondsum, atomsum);
  state_kernel<<<1, 256, 0, stream>>>(state, W + 26944, bondsum, atomsum, out_state);
}

// Round 6
// 491.396 us; speedup vs baseline: 1.3315x; 1.0740x over previous
//
#include <hip/hip_runtime.h>

#define B_   4
#define NB_  262144
#define NA_  8192
#define NB_SHIFT 18

typedef short bf16x8 __attribute__((ext_vector_type(8)));
typedef float f32x4  __attribute__((ext_vector_type(4)));

// ---------------- helpers ----------------
__device__ __forceinline__ float bflo(unsigned int u){ return __uint_as_float(u << 16); }
__device__ __forceinline__ float bfhi(unsigned int u){ return __uint_as_float(u & 0xffff0000u); }
__device__ __forceinline__ unsigned short f2bf(float f){
  unsigned int u = __float_as_uint(f);
  u += 0x7fffu + ((u >> 16) & 1u);   // round-to-nearest-even
  return (unsigned short)(u >> 16);
}
// HW packed f32->bf16 (RNE, same as f2bf) — 1 instr
__device__ __forceinline__ unsigned int packbf(float a, float b){
  unsigned int r;
  asm("v_cvt_pk_bf16_f32 %0, %1, %2" : "=v"(r) : "v"(a), "v"(b));
  return r;
}
__device__ __forceinline__ float softplus_f(float v){
  return fmaxf(v, 0.0f) + __logf(1.0f + __expf(-fabsf(v)));
}
// memory-op ordering fence for intra-wave cross-lane LDS communication.
// Only 3 per wave in the batched structure (vs 16 in nt-sequential — round 4/5 lesson:
// per-wave ILP inside each phase is the lever, not occupancy).
__device__ __forceinline__ void lds_fence(){
  asm volatile("" ::: "memory");
  __builtin_amdgcn_wave_barrier();
}

// ---------------- fused setup: prep (W concat) + swizzle + effective biases ----------
struct WPtrs { const float* p[18]; };

// blocks 0..153: prep; 154..249: swizzle; 250: be; 251: bv
__global__ __launch_bounds__(256) void setup_kernel(
    WPtrs wp, const float* __restrict__ state,
    float* __restrict__ W,
    unsigned short* __restrict__ Wb, unsigned short* __restrict__ Wbv,
    float* __restrict__ be, float* __restrict__ bv)
{
  const int blk = blockIdx.x;
  const int tid = threadIdx.x;
  if (blk < 154){
    int i = blk*256 + tid;
    if (i >= 39392) return;
    int idx = i;
    const int sizes[18] = {8192,64,4096,64,2048,32,
                           6144,64,4096,64,2048,32,
                           6144,64,4096,64,2048,32};
    #pragma unroll
    for (int s = 0; s < 18; ++s){
      if (idx < sizes[s]){ W[i] = wp.p[s][idx]; return; }
      idx -= sizes[s];
    }
  } else if (blk < 250){
    // swizzle e- and v-MLP weights into MFMA A-fragment order (bf16):
    // lane holds frag[k = quad*8 + j][col = lane&15]
    int i = (blk - 154)*256 + tid;      // [0, 24576)
    int j = i & 7, lane = (i >> 3) & 63;
    int quad = lane >> 4, l16 = lane & 15;
    int krow = quad*8 + j;
    float v;
    if (i < 14336){
      if (i < 8192){
        int g = i >> 9;  int mt = g & 3, kt = g >> 2;
        v = wp.p[0][(kt*32 + krow)*64 + mt*16 + l16];
      } else if (i < 12288){
        int g = (i - 8192) >> 9;  int mt = g & 3, kt = g >> 2;
        v = wp.p[2][(kt*32 + krow)*64 + mt*16 + l16];
      } else {
        int g = (i - 12288) >> 9;  int mt = g & 1, kt = g >> 1;
        v = wp.p[4][(kt*32 + krow)*32 + mt*16 + l16];
      }
      Wb[i] = f2bf(v);
    } else {
      int o = i - 14336;
      if (o < 4096){
        int g = o >> 9;  int mt = g & 3, kt = g >> 2;   // rows 0..63 (state folded)
        v = wp.p[6][(kt*32 + krow)*64 + mt*16 + l16];
      } else if (o < 8192){
        int g = (o - 4096) >> 9;  int mt = g & 3, kt = g >> 2;
        v = wp.p[8][(kt*32 + krow)*64 + mt*16 + l16];
      } else {
        int g = (o - 8192) >> 9;  int mt = g & 1, kt = g >> 1;
        v = wp.p[10][(kt*32 + krow)*32 + mt*16 + l16];
      }
      Wbv[o] = f2bf(v);
    }
  } else if (blk == 250){
    // be[b][64] = e_b1 + e_w1[96..127]^T state[b]  (reads raw inputs — no W dependency)
    int b = tid >> 6, j = tid & 63;
    const float* st = state + b*32;
    float a = wp.p[1][j];
    #pragma unroll
    for (int k = 0; k < 32; ++k) a = fmaf(st[k], wp.p[0][(96+k)*64 + j], a);
    be[b*64 + j] = a;
  } else {
    // bv[b][64] = v_b1 + v_w1[64..95]^T state[b]
    int b = tid >> 6, j = tid & 63;
    const float* st = state + b*32;
    float a = wp.p[7][j];
    #pragma unroll
    for (int k = 0; k < 32; ++k) a = fmaf(st[k], wp.p[6][(64+k)*64 + j], a);
    bv[b*64 + j] = a;
  }
}

// ---------------- CSR build: LDS-histogram counting sort ----------------
// hist folds its LDS histogram directly into global counts (reduce_kernel deleted).
__global__ __launch_bounds__(1024) void hist_lds_kernel(const int* __restrict__ ba1,
                                                        int* __restrict__ partials,
                                                        int* __restrict__ counts){
  __shared__ int lh[NA_];
  const int tid = threadIdx.x;
  const int blk = blockIdx.x;
  const int b = blk >> 4;
  const size_t base = (size_t)b*NB_ + (size_t)(blk & 15)*16384;
  #pragma unroll
  for (int i = tid; i < NA_; i += 1024) lh[i] = 0;
  __syncthreads();
  #pragma unroll
  for (int it = 0; it < 16; ++it)
    atomicAdd(&lh[ba1[base + it*1024 + tid]], 1);
  __syncthreads();
  #pragma unroll
  for (int i = tid; i < NA_; i += 1024){
    int v = lh[i];
    partials[blk*NA_ + i] = v;
    if (v) atomicAdd(&counts[b*NA_ + i], v);
  }
}

__global__ __launch_bounds__(1024) void scan_kernel(const int* __restrict__ counts,
                                                    int* __restrict__ offsets){
  __shared__ int s[1024];
  const int tid = threadIdx.x;
  const int base = tid * 32;
  int local[32]; int sum = 0;
  const uint4* cp = reinterpret_cast<const uint4*>(counts + base);
  #pragma unroll
  for (int q = 0; q < 8; ++q){
    uint4 v = cp[q];
    local[q*4+0] = (int)v.x; local[q*4+1] = (int)v.y;
    local[q*4+2] = (int)v.z; local[q*4+3] = (int)v.w;
    sum += (int)v.x + (int)v.y + (int)v.z + (int)v.w;
  }
  s[tid] = sum;
  __syncthreads();
  for (int off = 1; off < 1024; off <<= 1){
    int v = (tid >= off) ? s[tid - off] : 0;
    __syncthreads();
    s[tid] += v;
    __syncthreads();
  }
  int run = s[tid] - sum;
  #pragma unroll
  for (int i = 0; i < 32; ++i){
    offsets[base + i] = run; run += local[i];
  }
}

__global__ __launch_bounds__(256) void base_kernel(const int* __restrict__ offsets,
                                                   const int* __restrict__ partials,
                                                   int* __restrict__ bases){
  int t = blockIdx.x*256 + threadIdx.x;     // [0, 32768)
  int b = t >> 13, aa = t & (NA_-1);
  int run = offsets[t];
  #pragma unroll
  for (int lb = 0; lb < 16; ++lb){
    int g = (b*16 + lb)*NA_ + aa;
    bases[g] = run; run += partials[g];
  }
}

__global__ __launch_bounds__(1024) void fill_lds_kernel(const int* __restrict__ ba1,
                                                        const int* __restrict__ bases,
                                                        int* __restrict__ list){
  __shared__ int lh[NA_];
  const int tid = threadIdx.x;
  const int blk = blockIdx.x;
  const int b = blk >> 4;
  const size_t base = (size_t)b*NB_ + (size_t)(blk & 15)*16384;
  #pragma unroll
  for (int i = tid; i < NA_; i += 1024) lh[i] = 0;
  __syncthreads();
  #pragma unroll
  for (int it = 0; it < 16; ++it){
    int idx = it*1024 + tid;
    int a = ba1[base + idx];
    int rank = atomicAdd(&lh[a], 1);
    list[bases[blk*NA_ + a] + rank] = (int)((base + idx) & (NB_ - 1));
  }
}

// ---------------- stage 1: bonds MLP via MFMA, batched layers (round-2 structure) -----
// All 4 nt tiles advance through each layer together: 12-16 independent MFMAs per phase,
// only 3 fences per wave. LDS 64x72 shorts/wave (36 KB/block, 4 blocks/CU).
__global__ __launch_bounds__(256, 4) void bonds_kernel(
    const float* __restrict__ bonds,
    const int* __restrict__ ba1,
    const int* __restrict__ ba2,
    const float* __restrict__ atoms,
    const float* __restrict__ W,            // f32 concat (biases 2,3)
    const unsigned short* __restrict__ Wb,  // swizzled bf16 e-weights
    const float* __restrict__ be,           // effective bias1 [B][64]
    float* __restrict__ bonds_out)
{
  __shared__ unsigned short hred[4][64*72];
  const int tid  = threadIdx.x;
  const int wave = tid >> 6, lane = tid & 63;
  const int quad = lane >> 4, l16 = lane & 15;
  const int b = blockIdx.y;
  const int rowbase = blockIdx.x*256 + wave*64;
  unsigned short* H = &hred[wave][0];

  int r[4], g1[4], g2[4];
  #pragma unroll
  for (int nt = 0; nt < 4; ++nt){
    r[nt]  = rowbase + nt*16 + l16;
    g1[nt] = ba1[(size_t)b*NB_ + r[nt]];
    g2[nt] = ba2[(size_t)b*NB_ + r[nt]];
  }

  // ----- layer 1: [64 feat][96 k] x [96 k][64 bond] (state folded into bias) -----
  f32x4 acc[4][4] = {};    // [mt = feat tile][nt = bond tile]
  #pragma unroll
  for (int kt = 0; kt < 3; ++kt){
    bf16x8 wf[4];
    #pragma unroll
    for (int mt = 0; mt < 4; ++mt)
      wf[mt] = *(const bf16x8*)(Wb + ((kt*4 + mt)*64 + lane)*8);
    #pragma unroll
    for (int nt = 0; nt < 4; ++nt){
      const float* src;
      if      (kt == 0) src = atoms + ((size_t)b*NA_ + g1[nt])*32 + quad*8;
      else if (kt == 1) src = atoms + ((size_t)b*NA_ + g2[nt])*32 + quad*8;
      else              src = bonds + ((size_t)b*NB_ + r[nt])*32 + quad*8;
      float4 v0 = *(const float4*)(src);
      float4 v1 = *(const float4*)(src + 4);
      union { bf16x8 v; unsigned int u[4]; } xf;
      xf.u[0] = packbf(v0.x, v0.y);
      xf.u[1] = packbf(v0.z, v0.w);
      xf.u[2] = packbf(v1.x, v1.y);
      xf.u[3] = packbf(v1.z, v1.w);
      #pragma unroll
      for (int mt = 0; mt < 4; ++mt)
        acc[mt][nt] = __builtin_amdgcn_mfma_f32_16x16x32_bf16(wf[mt], xf.v, acc[mt][nt], 0, 0, 0);
    }
  }
  // bias + softplus -> H1 [bond][feat] stride 72
  {
    const float* b1v = be + b*64;
    #pragma unroll
    for (int mt = 0; mt < 4; ++mt){
      float4 bias = *(const float4*)(b1v + mt*16 + quad*4);
      #pragma unroll
      for (int nt = 0; nt < 4; ++nt){
        unsigned int lo = packbf(softplus_f(acc[mt][nt][0] + bias.x),
                                 softplus_f(acc[mt][nt][1] + bias.y));
        unsigned int hi = packbf(softplus_f(acc[mt][nt][2] + bias.z),
                                 softplus_f(acc[mt][nt][3] + bias.w));
        *reinterpret_cast<uint2*>(H + (nt*16 + l16)*72 + mt*16 + quad*4) = make_uint2(lo, hi);
      }
    }
  }
  lds_fence();   // H1 writes before cross-lane H1 reads

  // ----- layer 2: [64][64] -----
  f32x4 acc2[4][4] = {};
  #pragma unroll
  for (int kt = 0; kt < 2; ++kt){
    bf16x8 wf[4];
    #pragma unroll
    for (int mt = 0; mt < 4; ++mt)
      wf[mt] = *(const bf16x8*)(Wb + 8192 + ((kt*4 + mt)*64 + lane)*8);
    #pragma unroll
    for (int nt = 0; nt < 4; ++nt){
      bf16x8 hf = *(const bf16x8*)(H + (nt*16 + l16)*72 + kt*32 + quad*8);
      #pragma unroll
      for (int mt = 0; mt < 4; ++mt)
        acc2[mt][nt] = __builtin_amdgcn_mfma_f32_16x16x32_bf16(wf[mt], hf, acc2[mt][nt], 0, 0, 0);
    }
  }
  lds_fence();   // H1 reads before H2 overwrites
  {
    const float* b2v = W + 12352;
    #pragma unroll
    for (int mt = 0; mt < 4; ++mt){
      float4 bias = *(const float4*)(b2v + mt*16 + quad*4);
      #pragma unroll
      for (int nt = 0; nt < 4; ++nt){
        unsigned int lo = packbf(softplus_f(acc2[mt][nt][0] + bias.x),
                                 softplus_f(acc2[mt][nt][1] + bias.y));
        unsigned int hi = packbf(softplus_f(acc2[mt][nt][2] + bias.z),
                                 softplus_f(acc2[mt][nt][3] + bias.w));
        *reinterpret_cast<uint2*>(H + (nt*16 + l16)*72 + mt*16 + quad*4) = make_uint2(lo, hi);
      }
    }
  }
  lds_fence();   // H2 writes before cross-lane H2 reads

  // ----- layer 3: [32][64] -----
  f32x4 acc3[2][4] = {};
  #pragma unroll
  for (int kt = 0; kt < 2; ++kt){
    bf16x8 wf[2];
    #pragma unroll
    for (int mt = 0; mt < 2; ++mt)
      wf[mt] = *(const bf16x8*)(Wb + 12288 + ((kt*2 + mt)*64 + lane)*8);
    #pragma unroll
    for (int nt = 0; nt < 4; ++nt){
      bf16x8 hf = *(const bf16x8*)(H + (nt*16 + l16)*72 + kt*32 + quad*8);
      #pragma unroll
      for (int mt = 0; mt < 2; ++mt)
        acc3[mt][nt] = __builtin_amdgcn_mfma_f32_16x16x32_bf16(wf[mt], hf, acc3[mt][nt], 0, 0, 0);
    }
  }
  {
    const float* b3v = W + 14464;
    float4 bias0 = *(const float4*)(b3v + quad*4);
    float4 bias1 = *(const float4*)(b3v + 16 + quad*4);
    #pragma unroll
    for (int nt = 0; nt < 4; ++nt){
      float4 o0, o1;
      o0.x = softplus_f(acc3[0][nt][0] + bias0.x);
      o0.y = softplus_f(acc3[0][nt][1] + bias0.y);
      o0.z = softplus_f(acc3[0][nt][2] + bias0.z);
      o0.w = softplus_f(acc3[0][nt][3] + bias0.w);
      o1.x = softplus_f(acc3[1][nt][0] + bias1.x);
      o1.y = softplus_f(acc3[1][nt][1] + bias1.y);
      o1.z = softplus_f(acc3[1][nt][2] + bias1.z);
      o1.w = softplus_f(acc3[1][nt][3] + bias1.w);
      float* outp = bonds_out + ((size_t)b*NB_ + r[nt])*32 + quad*4;
      *reinterpret_cast<float4*>(outp)      = o0;
      *reinterpret_cast<float4*>(outp + 16) = o1;
    }
  }
}

// ---------------- gather: mean of bonds_out rows per atom -> packed bf16 (pre-divided) --
__global__ __launch_bounds__(256) void gather_kernel(
    const int* __restrict__ counts,
    const int* __restrict__ offsets,
    const int* __restrict__ list,
    const float* __restrict__ bonds_out,
    unsigned int* __restrict__ btap)
{
  int i = blockIdx.x*256 + threadIdx.x;   // [0, B*NA*8)
  int p = i & 7;
  int row = i >> 3;                        // b*NA + atom
  int b = row >> 13;                       // NA = 2^13
  int c = counts[row], o = offsets[row];
  const float* basep = bonds_out + (size_t)b*NB_*32 + p*4;
  float4 acc = make_float4(0.f, 0.f, 0.f, 0.f);
  int t = 0;
  for (; t + 2 <= c; t += 2){
    int i0 = list[o+t], i1 = list[o+t+1];
    float4 v0 = *(const float4*)(basep + (size_t)i0*32);
    float4 v1 = *(const float4*)(basep + (size_t)i1*32);
    acc.x += v0.x + v1.x; acc.y += v0.y + v1.y;
    acc.z += v0.z + v1.z; acc.w += v0.w + v1.w;
  }
  if (t < c){
    int i0 = list[o+t];
    float4 v0 = *(const float4*)(basep + (size_t)i0*32);
    acc.x += v0.x; acc.y += v0.y; acc.z += v0.z; acc.w += v0.w;
  }
  float inv = 1.0f / (float)c;
  btap[(size_t)row*16 + p*2    ] = packbf(acc.x*inv, acc.y*inv);
  btap[(size_t)row*16 + p*2 + 1] = packbf(acc.z*inv, acc.w*inv);
}

// ---------------- stage 2: atoms MLP via MFMA, batched layers ----------
// Wv: w1[96][64] @0 | b1 @6144 | w2 @6208 | b2 @10304 | w3 @10368 | b3 @12416
__global__ __launch_bounds__(256, 4) void atoms_kernel(
    const float* __restrict__ atoms,
    const float* __restrict__ Wv,
    const int* __restrict__ counts,
    const unsigned int* __restrict__ btap,   // pre-divided bf16 pairs
    const float* __restrict__ bv,            // effective bias1 [B][64]
    const unsigned short* __restrict__ Wbv,  // swizzled bf16 v-weights
    float* __restrict__ atoms_out,
    float* __restrict__ bondsum,
    float* __restrict__ atomsum)
{
  __shared__ unsigned short hred[4][64*72];
  const int tid  = threadIdx.x;
  const int wave = tid >> 6, lane = tid & 63;
  const int quad = lane >> 4, l16 = lane & 15;
  const int b = blockIdx.y;
  const int arowbase = blockIdx.x*256 + wave*64;
  unsigned short* H = &hred[wave][0];

  int arow[4], cnt[4];
  #pragma unroll
  for (int nt = 0; nt < 4; ++nt){
    arow[nt] = b*NA_ + arowbase + nt*16 + l16;
    cnt[nt]  = counts[arow[nt]];
  }

  float p1[8] = {0,0,0,0,0,0,0,0};   // bondsum partials (feats quad*8+j)
  float p2[8] = {0,0,0,0,0,0,0,0};   // atomsum partials

  // ----- layer 1 batched: kt=0 from btap (bf16, pre-divided), kt=1 from atoms -----
  f32x4 acc[4][4] = {};
  {
    bf16x8 wf[4];
    #pragma unroll
    for (int mt = 0; mt < 4; ++mt)
      wf[mt] = *(const bf16x8*)(Wbv + ((0*4 + mt)*64 + lane)*8);
    #pragma unroll
    for (int nt = 0; nt < 4; ++nt){
      union { uint4 q; bf16x8 v; } bt;
      bt.q = *(const uint4*)(btap + (size_t)arow[nt]*16 + quad*4);
      float cf = (float)cnt[nt];
      p1[0] += bflo(bt.q.x)*cf; p1[1] += bfhi(bt.q.x)*cf;
      p1[2] += bflo(bt.q.y)*cf; p1[3] += bfhi(bt.q.y)*cf;
      p1[4] += bflo(bt.q.z)*cf; p1[5] += bfhi(bt.q.z)*cf;
      p1[6] += bflo(bt.q.w)*cf; p1[7] += bfhi(bt.q.w)*cf;
      #pragma unroll
      for (int mt = 0; mt < 4; ++mt)
        acc[mt][nt] = __builtin_amdgcn_mfma_f32_16x16x32_bf16(wf[mt], bt.v, acc[mt][nt], 0, 0, 0);
    }
  }
  {
    bf16x8 wf[4];
    #pragma unroll
    for (int mt = 0; mt < 4; ++mt)
      wf[mt] = *(const bf16x8*)(Wbv + ((1*4 + mt)*64 + lane)*8);
    #pragma unroll
    for (int nt = 0; nt < 4; ++nt){
      const float* src = atoms + (size_t)arow[nt]*32 + quad*8;
      float4 v0 = *(const float4*)(src);
      float4 v1 = *(const float4*)(src + 4);
      union { bf16x8 v; unsigned int u[4]; } xf;
      xf.u[0] = packbf(v0.x, v0.y);
      xf.u[1] = packbf(v0.z, v0.w);
      xf.u[2] = packbf(v1.x, v1.y);
      xf.u[3] = packbf(v1.z, v1.w);
      #pragma unroll
      for (int mt = 0; mt < 4; ++mt)
        acc[mt][nt] = __builtin_amdgcn_mfma_f32_16x16x32_bf16(wf[mt], xf.v, acc[mt][nt], 0, 0, 0);
    }
  }
  {
    const float* b1v = bv + b*64;
    #pragma unroll
    for (int mt = 0; mt < 4; ++mt){
      float4 bias = *(const float4*)(b1v + mt*16 + quad*4);
      #pragma unroll
      for (int nt = 0; nt < 4; ++nt){
        unsigned int lo = packbf(softplus_f(acc[mt][nt][0] + bias.x),
                                 softplus_f(acc[mt][nt][1] + bias.y));
        unsigned int hi = packbf(softplus_f(acc[mt][nt][2] + bias.z),
                                 softplus_f(acc[mt][nt][3] + bias.w));
        *reinterpret_cast<uint2*>(H + (nt*16 + l16)*72 + mt*16 + quad*4) = make_uint2(lo, hi);
      }
    }
  }
  lds_fence();

  // ----- layer 2 -----
  f32x4 acc2[4][4] = {};
  #pragma unroll
  for (int kt = 0; kt < 2; ++kt){
    bf16x8 wf[4];
    #pragma unroll
    for (int mt = 0; mt < 4; ++mt)
      wf[mt] = *(const bf16x8*)(Wbv + 4096 + ((kt*4 + mt)*64 + lane)*8);
    #pragma unroll
    for (int nt = 0; nt < 4; ++nt){
      bf16x8 hf = *(const bf16x8*)(H + (nt*16 + l16)*72 + kt*32 + quad*8);
      #pragma unroll
      for (int mt = 0; mt < 4; ++mt)
        acc2[mt][nt] = __builtin_amdgcn_mfma_f32_16x16x32_bf16(wf[mt], hf, acc2[mt][nt], 0, 0, 0);
    }
  }
  lds_fence();
  {
    const float* b2v = Wv + 10304;
    #pragma unroll
    for (int mt = 0; mt < 4; ++mt){
      float4 bias = *(const float4*)(b2v + mt*16 + quad*4);
      #pragma unroll
      for (int nt = 0; nt < 4; ++nt){
        unsigned int lo = packbf(softplus_f(acc2[mt][nt][0] + bias.x),
                                 softplus_f(acc2[mt][nt][1] + bias.y));
        unsigned int hi = packbf(softplus_f(acc2[mt][nt][2] + bias.z),
                                 softplus_f(acc2[mt][nt][3] + bias.w));
        *reinterpret_cast<uint2*>(H + (nt*16 + l16)*72 + mt*16 + quad*4) = make_uint2(lo, hi);
      }
    }
  }
  lds_fence();

  // ----- layer 3 -----
  f32x4 acc3[2][4] = {};
  #pragma unroll
  for (int kt = 0; kt < 2; ++kt){
    bf16x8 wf[2];
    #pragma unroll
    for (int mt = 0; mt < 2; ++mt)
      wf[mt] = *(const bf16x8*)(Wbv + 8192 + ((kt*2 + mt)*64 + lane)*8);
    #pragma unroll
    for (int nt = 0; nt < 4; ++nt){
      bf16x8 hf = *(const bf16x8*)(H + (nt*16 + l16)*72 + kt*32 + quad*8);
      #pragma unroll
      for (int mt = 0; mt < 2; ++mt)
        acc3[mt][nt] = __builtin_amdgcn_mfma_f32_16x16x32_bf16(wf[mt], hf, acc3[mt][nt], 0, 0, 0);
    }
  }
  {
    const float* b3v = Wv + 12416;
    float4 bias0 = *(const float4*)(b3v + quad*4);
    float4 bias1 = *(const float4*)(b3v + 16 + quad*4);
    #pragma unroll
    for (int nt = 0; nt < 4; ++nt){
      float4 o0, o1;
      o0.x = softplus_f(acc3[0][nt][0] + bias0.x);
      o0.y = softplus_f(acc3[0][nt][1] + bias0.y);
      o0.z = softplus_f(acc3[0][nt][2] + bias0.z);
      o0.w = softplus_f(acc3[0][nt][3] + bias0.w);
      o1.x = softplus_f(acc3[1][nt][0] + bias1.x);
      o1.y = softplus_f(acc3[1][nt][1] + bias1.y);
      o1.z = softplus_f(acc3[1][nt][2] + bias1.z);
      o1.w = softplus_f(acc3[1][nt][3] + bias1.w);
      p2[0] += o0.x; p2[1] += o0.y; p2[2] += o0.z; p2[3] += o0.w;
      p2[4] += o1.x; p2[5] += o1.y; p2[6] += o1.z; p2[7] += o1.w;
      float* outp = atoms_out + (size_t)arow[nt]*32 + quad*4;
      *reinterpret_cast<float4*>(outp)      = o0;
      *reinterpret_cast<float4*>(outp + 16) = o1;
    }
  }

  // reduce partials across the 16 lanes of each quad-group, one atomic per feat
  #pragma unroll
  for (int j = 0; j < 8; ++j){
    float v = p1[j];
    v += __shfl_xor(v, 1); v += __shfl_xor(v, 2);
    v += __shfl_xor(v, 4); v += __shfl_xor(v, 8);
    if (l16 == 0) unsafeAtomicAdd(&bondsum[b*32 + quad*8 + j], v);
    float w = p2[j];
    w += __shfl_xor(w, 1); w += __shfl_xor(w, 2);
    w += __shfl_xor(w, 4); w += __shfl_xor(w, 8);
    if (l16 == 0) unsafeAtomicAdd(&atomsum[b*32 + (j>>2)*16 + quad*4 + (j&3)], w);
  }
}

// ---------------- stage 3: state MLP (96->64->64->32), 4 rows ----------------
__global__ __launch_bounds__(256) void state_kernel(
    const float* __restrict__ state,
    const float* __restrict__ W,
    const float* __restrict__ bondsum,
    const float* __restrict__ atomsum,
    float* __restrict__ state_out)
{
  __shared__ float uin[4][96];
  __shared__ float h1s[4][64];
  __shared__ float h2s[4][64];
  const int tid = threadIdx.x;
  const int b = tid >> 6;
  const int j = tid & 63;
  if (j < 32){
    uin[b][j]      = bondsum[b*32 + j] * (1.0f/(float)NB_);
    uin[b][32 + j] = atomsum[b*32 + j] * (1.0f/(float)NA_);
    uin[b][64 + j] = state[(size_t)b*32 + j];
  }
  __syncthreads();
  float a1 = W[6144 + j];
  for (int k = 0; k < 96; ++k) a1 = fmaf(uin[b][k], W[k*64 + j], a1);
  h1s[b][j] = softplus_f(a1);
  __syncthreads();
  float a2 = W[10304 + j];
  for (int k = 0; k < 64; ++k) a2 = fmaf(h1s[b][k], W[6208 + k*64 + j], a2);
  h2s[b][j] = softplus_f(a2);
  __syncthreads();
  if (j < 32){
    float a3 = W[12416 + j];
    for (int k = 0; k < 64; ++k) a3 = fmaf(h2s[b][k], W[10368 + k*32 + j], a3);
    state_out[b*32 + j] = softplus_f(a3);
  }
}

// ---------------- launcher ----------------
// ws (4-byte units): counts[32768]@0 | offsets@32768 | Wbv u16[10240]@65536 (5120 dw) |
//   list[1048576]@98304 | btap[524288]@1146880 | bondsum[128]@1671168 | atomsum[128]@1671296 |
//   W f32[39392]@1671424 | Wb u16[14336]@1710816 (7168 dw) | be[256]@1717984 | bv[256]@1718240
// Aliases: partials@list (dead before fill writes list); bases@btap (dead before gather).
extern "C" void kernel_launch(void* const* d_in, const int* in_sizes, int n_in,
                              void* d_out, int out_size, void* d_ws, size_t ws_size,
                              hipStream_t stream)
{
  (void)in_sizes; (void)n_in; (void)out_size; (void)ws_size;
  const float* bonds = (const float*)d_in[0];
  const int*   ba1   = (const int*)d_in[1];
  const int*   ba2   = (const int*)d_in[2];
  const float* atoms = (const float*)d_in[3];
  const float* state = (const float*)d_in[4];

  int*          counts  = (int*)d_ws;
  int*          offsets = counts + 32768;
  unsigned short* Wbv   = (unsigned short*)((unsigned int*)d_ws + 65536);
  int*          list    = counts + 98304;
  unsigned int* btap    = (unsigned int*)d_ws + 1146880;
  float*        bondsum = (float*)d_ws + 1671168;
  float*        atomsum = (float*)d_ws + 1671296;
  float*        W       = (float*)d_ws + 1671424;
  unsigned short* Wb    = (unsigned short*)((unsigned int*)d_ws + 1710816);
  float*        be      = (float*)d_ws + 1717984;
  float*        bv      = (float*)d_ws + 1718240;

  int* partials = list;           // dead before fill overwrites list
  int* bases    = (int*)btap;     // dead before gather overwrites btap

  hipMemsetAsync(counts, 0, 32768 * sizeof(int), stream);
  hipMemsetAsync(bondsum, 0, 256 * sizeof(float), stream);

  WPtrs wp;
  for (int s = 0; s < 18; ++s) wp.p[s] = (const float*)d_in[5 + s];
  setup_kernel<<<252, 256, 0, stream>>>(wp, state, W, Wb, Wbv, be, bv);

  // CSR build — counting sort with LDS histograms (hist folds counts directly)
  hist_lds_kernel<<<64, 1024, 0, stream>>>(ba1, partials, counts);
  scan_kernel<<<1, 1024, 0, stream>>>(counts, offsets);
  base_kernel<<<128, 256, 0, stream>>>(offsets, partials, bases);
  fill_lds_kernel<<<64, 1024, 0, stream>>>(ba1, bases, list);

  float* out_bonds = (float*)d_out;
  float* out_atoms = out_bonds + (size_t)B_*NB_*32;
  float* out_state = out_atoms + (size_t)B_*NA_*32;

  bonds_kernel<<<dim3(NB_/256, B_), 256, 0, stream>>>(bonds, ba1, ba2, atoms,
                                                      W, Wb, be, out_bonds);
  gather_kernel<<<(B_*NA_*8)/256, 256, 0, stream>>>(counts, offsets, list, out_bonds, btap);
  atoms_kernel<<<dim3(NA_/256, B_), 256, 0, stream>>>(atoms, W + 14496,
                                                      counts, btap, bv, Wbv, out_atoms,
                                                      bondsum, atomsum);
  state_kernel<<<1, 256, 0, stream>>>(state, W + 26944, bondsum, atomsum, out_state);
}